// Round 1
// baseline (453.150 us; speedup 1.0000x reference)
//
#include <hip/hip_runtime.h>
#include <hip/hip_bf16.h>

using bf16 = __hip_bfloat16;
typedef __bf16 bf16x8_t __attribute__((ext_vector_type(8)));
typedef __bf16 bf16x4_t __attribute__((ext_vector_type(4)));
typedef float f32x4  __attribute__((ext_vector_type(4)));
typedef float f32x16 __attribute__((ext_vector_type(16)));

#define AS1 __attribute__((address_space(1)))
#define AS3 __attribute__((address_space(3)))

__device__ __forceinline__ void gll16(const void* g, void* l) {
  __builtin_amdgcn_global_load_lds((const AS1 void*)g, (AS3 void*)l, 16u, 0, 0u);
}

__device__ __forceinline__ __bf16 tobf(float f) {
  bf16 h = __float2bfloat16(f);
  return __builtin_bit_cast(__bf16, h);
}

// ---------------------------------------------------------------- cvt fp32->bf16
__global__ __launch_bounds__(256) void k_cvt(
    const float* __restrict__ x,  const float* __restrict__ wq,
    const float* __restrict__ wk, const float* __restrict__ wv,
    const float* __restrict__ wo,
    bf16* __restrict__ xb,  bf16* __restrict__ wqb, bf16* __restrict__ wkb,
    bf16* __restrict__ wvb, bf16* __restrict__ wob) {
  size_t id = (size_t)blockIdx.x * 256 + threadIdx.x;   // float4 units
  const float* s; bf16* d; size_t off;
  if (id < 2097152) { s = x; d = xb; off = id; }
  else {
    size_t r = id - 2097152;
    unsigned w = (unsigned)(r >> 20);
    off = r & 1048575u;
    s = (w == 0) ? wq : (w == 1) ? wk : (w == 2) ? wv : wo;
    d = (w == 0) ? wqb : (w == 1) ? wkb : (w == 2) ? wvb : wob;
  }
  const float4 v = ((const float4*)s)[off];
  bf16x4_t o = { tobf(v.x), tobf(v.y), tobf(v.z), tobf(v.w) };
  *(bf16x4_t*)(d + off * 4) = o;
}

// ---------------------------------------------------------------- lambda scalar
__global__ __launch_bounds__(256) void k_lam(
    const float* __restrict__ lq1, const float* __restrict__ lk1,
    const float* __restrict__ lq2, const float* __restrict__ lk2,
    float* __restrict__ lam) {
  __shared__ float r1[4], r2[4];
  int t = threadIdx.x;
  float a = lq1[t] * lk1[t];
  float b = lq2[t] * lk2[t];
#pragma unroll
  for (int s = 1; s < 64; s <<= 1) { a += __shfl_xor(a, s); b += __shfl_xor(b, s); }
  if ((t & 63) == 0) { r1[t >> 6] = a; r2[t >> 6] = b; }
  __syncthreads();
  if (t == 0) {
    float s1 = r1[0] + r1[1] + r1[2] + r1[3];
    float s2 = r2[0] + r2[1] + r2[2] + r2[3];
    *lam = expf(s1) - expf(s2) + 0.2f;
  }
}

// ---------------------------------------------------------------- ring GEMM core
// 512 threads, BM=128 x BN=256, BK=64, ring-of-3 LDS slots (48 KiB each).
// Tile k+2 staged while tile k computes; counted s_waitcnt vmcnt(6) + raw
// s_barrier per K-tile (never drains to 0 in steady state). 8 waves of 64x64
// (wm = wave>>2 row-half, wn = wave&3 column-frag set given by bfrow[]).
// SWAP=true: acc lane-field = row, reg-field = 4 consecutive cols.
__device__ __forceinline__ void stage_ring(
    const bf16* __restrict__ A, const bf16* __restrict__ B,
    int m0, int n0, int k0, bf16* slot) {
  const int tid = threadIdx.x;
#pragma unroll
  for (int j = 0; j < 2; ++j) {             // A: 128x64
    int id = tid + j * 512;
    int row = id >> 3, c = id & 7, sc = c ^ (row & 7);
    gll16(A + (size_t)(m0 + row) * 2048 + k0 + sc * 8, slot + id * 8);
  }
#pragma unroll
  for (int j = 0; j < 4; ++j) {             // B: 256x64 at elem offset 8192
    int id = tid + j * 512;
    int row = id >> 3, c = id & 7, sc = c ^ (row & 7);
    gll16(B + (size_t)(n0 + row) * 2048 + k0 + sc * 8, slot + 8192 + id * 8);
  }
}

template<bool SWAP>
__device__ __forceinline__ void ring_gemm(
    const bf16* __restrict__ A, const bf16* __restrict__ B,
    int m0, int n0, bf16 (*ring)[24576], f32x4 (&acc)[4][4],
    const int (&bfrow)[4]) {
  const int tid  = threadIdx.x;
  const int lane = tid & 63;
  const int g = lane >> 4, l15 = lane & 15, l7 = lane & 7;
  const int wm = tid >> 8;                  // wave>>2

  stage_ring(A, B, m0, n0, 0,  ring[0]);    // tiles 0,1 in flight (12 loads)
  stage_ring(A, B, m0, n0, 64, ring[1]);
  asm volatile("s_waitcnt vmcnt(6)\n\ts_barrier" ::: "memory");  // tile0 landed

  int s = 0;
  for (int k = 0; k < 32; ++k) {
    if (k < 30) {                           // stage tile k+2 into slot (k+2)%3
      int sp = s + 2; if (sp >= 3) sp -= 3; // == (k-1)%3: freed at barrier k-1
      stage_ring(A, B, m0, n0, (k + 2) * 64, ring[sp]);
    }
    const bf16* lA = ring[s];
    const bf16* lB = ring[s] + 8192;
#pragma unroll
    for (int ks = 0; ks < 2; ++ks) {
      const int pc = ((ks * 4 + g) ^ l7) * 8;
      bf16x8_t af[4], bv[4];
#pragma unroll
      for (int mt = 0; mt < 4; ++mt)
        af[mt] = *(const bf16x8_t*)(lA + (wm * 64 + mt * 16 + l15) * 64 + pc);
#pragma unroll
      for (int nt = 0; nt < 4; ++nt)
        bv[nt] = *(const bf16x8_t*)(lB + (bfrow[nt] + l15) * 64 + pc);
      __builtin_amdgcn_s_setprio(1);
#pragma unroll
      for (int mt = 0; mt < 4; ++mt)
#pragma unroll
        for (int nt = 0; nt < 4; ++nt) {
          if (SWAP)
            acc[mt][nt] = __builtin_amdgcn_mfma_f32_16x16x32_bf16(
                bv[nt], af[mt], acc[mt][nt], 0, 0, 0);
          else
            acc[mt][nt] = __builtin_amdgcn_mfma_f32_16x16x32_bf16(
                af[mt], bv[nt], acc[mt][nt], 0, 0, 0);
        }
      __builtin_amdgcn_s_setprio(0);
    }
    // per-wave: 6 oldest in flight = tile k+1 -> landed after this wait;
    // barrier makes every wave's share visible before tile k+1 is read.
    if (k < 30)       asm volatile("s_waitcnt vmcnt(6)\n\ts_barrier" ::: "memory");
    else if (k == 30) asm volatile("s_waitcnt vmcnt(0)\n\ts_barrier" ::: "memory");
    s = (s == 2) ? 0 : s + 1;
  }
}

// col-frag permutation: wave wn owns strips {j2*32..+31} and {j2*32+64..+95}
// inside its 128-col norm group p, so rotary pairs (j, j+64) are wave-local.
__device__ __forceinline__ void make_bfrow(int wn, int (&bfrow)[4]) {
  const int p = wn >> 1, j2 = wn & 1;
#pragma unroll
  for (int nt = 0; nt < 4; ++nt)
    bfrow[nt] = p * 128 + j2 * 32 + (nt & 1) * 16 + (nt >> 1) * 64;
}

// ---------------------------------------------------------------- QKV projection
__global__ __launch_bounds__(512, 2) void k_gemm_qkv(
    const bf16* __restrict__ xb,
    const bf16* __restrict__ wqb, const bf16* __restrict__ wkb,
    const bf16* __restrict__ wvb,
    bf16* __restrict__ q1, bf16* __restrict__ q2,
    bf16* __restrict__ k1, bf16* __restrict__ k2,
    bf16* __restrict__ vt) {
  __shared__ __align__(16) bf16 ring[3][24576];   // 144 KiB
  __shared__ float ex[8][64];
  __shared__ float lCs[64], lSn[64];
  const int z  = blockIdx.z;
  const int m0 = blockIdx.y * 128, n0 = blockIdx.x * 256;
  const int nh = blockIdx.x;                      // BN=256 == one head
  const int tid = threadIdx.x, lane = tid & 63, wave = tid >> 6;
  const int wm = wave >> 2, wn = wave & 3;
  const int g = lane >> 4, l15 = lane & 15;
  const int p = wn >> 1, j2 = wn & 1;
  int bfrow[4];
  make_bfrow(wn, bfrow);
  f32x4 acc[4][4] = {};

  if (z < 2) {
    const bf16* Bm = z ? wkb : wqb;
    ring_gemm<true>(xb, Bm, m0, n0, ring, acc, bfrow);

    // fused rmsnorm + rotary epilogue (norm group = 128 cols = wave pair)
    if (tid < 64) {
      float fr = exp2f(-(float)tid * 0.20762050593045951f);  // log2(10000)/64
      float sn, cs;
      sincosf((float)nh * fr, &sn, &cs);
      lCs[tid] = cs; lSn[tid] = sn;
    }
    float ssown[4];
#pragma unroll
    for (int mt = 0; mt < 4; ++mt) {
      float ss = 0.f;
#pragma unroll
      for (int nt = 0; nt < 4; ++nt)
#pragma unroll
        for (int r = 0; r < 4; ++r) ss += acc[mt][nt][r] * acc[mt][nt][r];
      ss += __shfl_xor(ss, 16);
      ss += __shfl_xor(ss, 32);
      ssown[mt] = ss;
      if (g == 0) ex[wave][mt * 16 + l15] = ss;
    }
    __syncthreads();
    bf16* dst = z ? (p ? k2 : k1) : (p ? q2 : q1);
#pragma unroll
    for (int mt = 0; mt < 4; ++mt) {
      const float sst = ssown[mt] + ex[wave ^ 1][mt * 16 + l15];
      const float inv = rsqrtf(sst * (1.0f / 128.0f) + 1.1920929e-07f);
      const int tok = m0 + wm * 64 + mt * 16 + l15;
      const size_t base = ((size_t)tok * 8 + nh) * 128;
#pragma unroll
      for (int nt2 = 0; nt2 < 2; ++nt2) {
        const int jb = j2 * 32 + nt2 * 16 + 4 * g;
        bf16x4_t o1v, o2v;
#pragma unroll
        for (int r = 0; r < 4; ++r) {
          float cs = lCs[jb + r], sn = lSn[jb + r];
          float x1 = acc[mt][nt2][r] * inv;
          float x2 = acc[mt][nt2 + 2][r] * inv;
          o1v[r] = tobf(x1 * cs + x2 * sn);
          o2v[r] = tobf(x2 * cs - x1 * sn);
        }
        *(bf16x4_t*)(dst + base + jb)      = o1v;
        *(bf16x4_t*)(dst + base + jb + 64) = o2v;
      }
    }
  } else {
    ring_gemm<false>(xb, wvb, m0, n0, ring, acc, bfrow);
    // V transposed to (bh, hd, t): unswapped reg-field = 4 consecutive rows
#pragma unroll
    for (int mt = 0; mt < 4; ++mt)
#pragma unroll
      for (int nt = 0; nt < 4; ++nt) {
        int rb = m0 + wm * 64 + mt * 16 + 4 * g;
        int hd = bfrow[nt] + l15;
        int b = rb >> 11, t = rb & 2047;
        bf16x4_t pv;
#pragma unroll
        for (int r = 0; r < 4; ++r) pv[r] = tobf(acc[mt][nt][r]);
        *(bf16x4_t*)(vt + ((size_t)((b * 8 + nh) * 256 + hd)) * 2048 + t) = pv;
      }
  }
}

// ---------------------------------------------------------------- output GEMM
__global__ __launch_bounds__(512, 2) void k_gemm_out(
    const bf16* __restrict__ yb, const bf16* __restrict__ wob,
    float* __restrict__ outp) {
  __shared__ __align__(16) bf16 ring[3][24576];
  const int m0 = blockIdx.y * 128, n0 = blockIdx.x * 256;
  const int tid = threadIdx.x, lane = tid & 63, wave = tid >> 6;
  const int wm = wave >> 2, wn = wave & 3;
  const int g = lane >> 4, l15 = lane & 15;
  int bfrow[4];
  make_bfrow(wn, bfrow);
  f32x4 acc[4][4] = {};
  ring_gemm<true>(yb, wob, m0, n0, ring, acc, bfrow);
#pragma unroll
  for (int mt = 0; mt < 4; ++mt)
#pragma unroll
    for (int nt = 0; nt < 4; ++nt) {
      int row = m0 + wm * 64 + mt * 16 + l15;
      int col = n0 + bfrow[nt] + 4 * g;
      f32x4 v;
#pragma unroll
      for (int r = 0; r < 4; ++r) v[r] = acc[mt][nt][r] * 0.8f;
      *(f32x4*)(outp + (size_t)row * 2048 + col) = v;
    }
}

// ---------------------------------------------------------------- flash attention
// 256 blocks (pair, bh): q-tiles qtB=31-pair then qtA=pair -> 33 k-iters each.
// Double-buffered K1/K2/V^T staging, one barrier per k-iter; P stays in regs
// (shfl_xor(32) C->B layout conversion).
__global__ __launch_bounds__(256, 1) void k_flash(
    const bf16* __restrict__ q1b, const bf16* __restrict__ q2b,
    const bf16* __restrict__ k1b, const bf16* __restrict__ k2b,
    const bf16* __restrict__ vtb, const float* __restrict__ lamp,
    bf16* __restrict__ yb) {
  __shared__ __align__(16) bf16 smem[65536];  // 128 KB
  const int tid  = threadIdx.x;
  const int lane = tid & 63, wave = tid >> 6;
  const int pair = blockIdx.x;           // 0..15
  const int bh = blockIdx.y;
  const int b = bh >> 3, nh = bh & 7;
  const int at = wave & 1, qg = wave >> 1;
  const int l31 = lane & 31, g5 = lane >> 5, l7 = lane & 7;
  const float scale = 0.08838834764831845f;  // 1/sqrt(128)
  const float lam = *lamp;

  auto stage = [&](int kt, int buf) {
    bf16* dst = smem + buf * 32768;
    const int k0 = kt * 64;
#pragma unroll
    for (int it = 0; it < 4; ++it) {
      int id = tid + it * 256;
      int row = id >> 4, c = id & 15;
      int sc = (c & 8) | ((c & 7) ^ (row & 7));
      size_t goff = ((size_t)(b * 2048 + k0 + row) * 8 + nh) * 128 + sc * 8;
      gll16(k1b + goff, dst + id * 8);
      gll16(k2b + goff, dst + 8192 + id * 8);
    }
#pragma unroll
    for (int it = 0; it < 8; ++it) {
      int id = tid + it * 256;
      int row = id >> 3, c = id & 7;
      int sc = c ^ (row & 7);
      gll16(vtb + ((size_t)(bh * 256 + row)) * 2048 + k0 + sc * 8,
            dst + 16384 + id * 8);
    }
  };

  bf16x8_t qf[8];
  auto loadQ = [&](int qt) {
    int qglob = qt * 64 + qg * 32 + l31;
    const bf16* qp = (at ? q2b : q1b) +
                     ((size_t)(b * 2048 + qglob) * 8 + nh) * 128 + g5 * 8;
#pragma unroll
    for (int ks = 0; ks < 8; ++ks) qf[ks] = *(const bf16x8_t*)(qp + ks * 16);
  };

  f32x16 O[8];
  float mrun, lrun;
  auto resetO = [&]() {
#pragma unroll
    for (int i = 0; i < 8; ++i)
#pragma unroll
      for (int j = 0; j < 16; ++j) O[i][j] = 0.f;
    mrun = -1e30f; lrun = 0.f;
  };

  auto step = [&](int kt, int buf, int qt) {
    const bf16* lk = smem + buf * 32768 + (at ? 8192 : 0);
    const bf16* lv = smem + buf * 32768 + 16384;
    const int k0 = kt * 64;
    const int qglob = qt * 64 + qg * 32 + l31;

    f32x16 s0, s1;
#pragma unroll
    for (int j = 0; j < 16; ++j) { s0[j] = 0.f; s1[j] = 0.f; }
#pragma unroll
    for (int ks = 0; ks < 8; ++ks) {
      int cl = ks * 2 + g5;
      int pc = (cl & 8) | ((cl & 7) ^ l7);
      bf16x8_t a0 = *(const bf16x8_t*)(lk + l31 * 128 + pc * 8);
      bf16x8_t a1 = *(const bf16x8_t*)(lk + (32 + l31) * 128 + pc * 8);
      s0 = __builtin_amdgcn_mfma_f32_32x32x16_bf16(a0, qf[ks], s0, 0, 0, 0);
      s1 = __builtin_amdgcn_mfma_f32_32x32x16_bf16(a1, qf[ks], s1, 0, 0, 0);
    }

    const bool diag = (kt == qt);
    float rmax = -3.0e38f;
#pragma unroll
    for (int r = 0; r < 16; ++r) {
      int key0 = k0 + (r & 3) + 8 * (r >> 2) + 4 * g5;
      float v0 = s0[r] * scale;
      float v1 = s1[r] * scale;
      if (diag) {
        if (key0 > qglob)      v0 = -1e30f;
        if (key0 + 32 > qglob) v1 = -1e30f;
      }
      s0[r] = v0; s1[r] = v1;
      rmax = fmaxf(rmax, fmaxf(v0, v1));
    }
    rmax = fmaxf(rmax, __shfl_xor(rmax, 32));
    float mnew = fmaxf(mrun, rmax);
    float alpha = __expf(mrun - mnew);
    float psum = 0.f;
#pragma unroll
    for (int r = 0; r < 16; ++r) {
      float p0 = __expf(s0[r] - mnew);
      float p1 = __expf(s1[r] - mnew);
      s0[r] = p0; s1[r] = p1;
      psum += p0 + p1;
    }
    psum += __shfl_xor(psum, 32);
    lrun = lrun * alpha + psum;
    mrun = mnew;
#pragma unroll
    for (int i = 0; i < 8; ++i) O[i] *= alpha;

#pragma unroll
    for (int sl = 0; sl < 4; ++sl) {
      const int h = sl & 1;
      bf16x4_t lo, hi;
#pragma unroll
      for (int j = 0; j < 4; ++j) {
        float vl = (sl < 2) ? s0[h * 8 + j]     : s1[h * 8 + j];
        float vh = (sl < 2) ? s0[h * 8 + 4 + j] : s1[h * 8 + 4 + j];
        lo[j] = tobf(vl); hi[j] = tobf(vh);
      }
      bf16x4_t send = g5 ? lo : hi;
      int2 si = __builtin_bit_cast(int2, send);
      int2 ri;
      ri.x = __shfl_xor(si.x, 32);
      ri.y = __shfl_xor(si.y, 32);
      bf16x4_t recv = __builtin_bit_cast(bf16x4_t, ri);
      bf16x4_t f0 = g5 ? recv : lo;
      bf16x4_t f1 = g5 ? hi : recv;
      bf16x8_t pf = { f0[0], f0[1], f0[2], f0[3], f1[0], f1[1], f1[2], f1[3] };

      const int cl = sl * 2 + g5;
#pragma unroll
      for (int mt = 0; mt < 8; ++mt) {
        bf16x8_t vf = *(const bf16x8_t*)(lv + (mt * 32 + l31) * 64 + (cl ^ l7) * 8);
        O[mt] = __builtin_amdgcn_mfma_f32_32x32x16_bf16(vf, pf, O[mt], 0, 0, 0);
      }
    }
  };

  auto finish = [&](int qt, bf16* cb) {
    const int qglob = qt * 64 + qg * 32 + l31;
    const float invl = 1.f / lrun;
    __syncthreads();
    if (at) {
      const float f = lam * invl;
#pragma unroll
      for (int mt = 0; mt < 8; ++mt)
#pragma unroll
        for (int rq = 0; rq < 4; ++rq) {
          int hd = mt * 32 + 8 * rq + 4 * g5;
          bf16x4_t pv;
#pragma unroll
          for (int i = 0; i < 4; ++i) pv[i] = tobf(O[mt][rq * 4 + i] * f);
          *(bf16x4_t*)(cb + (size_t)(qg * 32 + l31) * 264 + hd) = pv;
        }
    }
    __syncthreads();
    if (!at) {
#pragma unroll
      for (int mt = 0; mt < 8; ++mt)
#pragma unroll
        for (int rq = 0; rq < 4; ++rq) {
          int hd = mt * 32 + 8 * rq + 4 * g5;
          bf16x4_t o2 = *(const bf16x4_t*)(cb + (size_t)(qg * 32 + l31) * 264 + hd);
          bf16x4_t pv;
#pragma unroll
          for (int i = 0; i < 4; ++i)
            pv[i] = tobf(O[mt][rq * 4 + i] * invl - (float)o2[i]);
          *(bf16x4_t*)(yb + (size_t)(b * 2048 + qglob) * 2048 + nh * 256 + hd) = pv;
        }
    }
  };

  const int qtB = 31 - pair, qtA = pair;

  loadQ(qtB);
  resetO();
  stage(0, 0);
  for (int kt = 0; kt <= qtB; ++kt) {
    __syncthreads();
    if (kt < qtB) stage(kt + 1, (kt + 1) & 1);
    else          stage(0, (kt + 1) & 1);        // prefetch segment A kt=0
    step(kt, kt & 1, qtB);
  }
  finish(qtB, smem + (qtB & 1) * 32768);

  loadQ(qtA);
  resetO();
  for (int kt = 0; kt <= qtA; ++kt) {
    __syncthreads();
    if (kt < qtA) stage(kt + 1, (qtB + kt + 2) & 1);
    step(kt, (qtB + 1 + kt) & 1, qtA);
  }
  finish(qtA, smem + 32768);
}

// ---------------------------------------------------------------- launch
extern "C" void kernel_launch(void* const* d_in, const int* in_sizes, int n_in,
                              void* d_out, int out_size, void* d_ws, size_t ws_size,
                              hipStream_t stream) {
  (void)in_sizes; (void)n_in; (void)out_size; (void)ws_size;
  const float* x   = (const float*)d_in[0];
  const float* wq  = (const float*)d_in[1];
  const float* wk  = (const float*)d_in[2];
  const float* wv  = (const float*)d_in[3];
  const float* wo  = (const float*)d_in[4];
  const float* lq1 = (const float*)d_in[5];
  const float* lk1 = (const float*)d_in[6];
  const float* lq2 = (const float*)d_in[7];
  const float* lk2 = (const float*)d_in[8];
  float* out = (float*)d_out;

  char* p = (char*)d_ws;
  float* lam = (float*)p;            p += 256;
  bf16* xb  = (bf16*)p;              p += (size_t)4096 * 2048 * 2;
  bf16* wqb = (bf16*)p;              p += (size_t)2048 * 2048 * 2;
  bf16* wkb = (bf16*)p;              p += (size_t)2048 * 2048 * 2;
  bf16* wvb = (bf16*)p;              p += (size_t)2048 * 2048 * 2;
  bf16* wob = (bf16*)p;              p += (size_t)2048 * 2048 * 2;
  bf16* vt  = (bf16*)p;              p += (size_t)4096 * 2048 * 2;
  bf16* q1b = (bf16*)p;              p += (size_t)4096 * 1024 * 2;
  bf16* q2b = (bf16*)p;              p += (size_t)4096 * 1024 * 2;
  bf16* k1b = (bf16*)p;              p += (size_t)4096 * 1024 * 2;
  bf16* k2b = (bf16*)p;              p += (size_t)4096 * 1024 * 2;
  bf16* yb  = (bf16*)p;              p += (size_t)4096 * 2048 * 2;

  k_cvt<<<24576, 256, 0, stream>>>(x, wq, wk, wv, wo, xb, wqb, wkb, wvb, wob);
  k_lam<<<1, 256, 0, stream>>>(lq1, lk1, lq2, lk2, lam);
  k_gemm_qkv<<<dim3(8, 32, 3), 512, 0, stream>>>(xb, wqb, wkb, wvb,
                                                 q1b, q2b, k1b, k2b, vt);
  k_flash<<<dim3(16, 16), 256, 0, stream>>>(q1b, q2b, k1b, k2b, vt, lam, yb);
  k_gemm_out<<<dim3(8, 32), 512, 0, stream>>>(yb, wob, out);
}

// Round 2
// 433.972 us; speedup vs baseline: 1.0442x; 1.0442x over previous
//
#include <hip/hip_runtime.h>
#include <hip/hip_bf16.h>

using bf16 = __hip_bfloat16;
typedef __bf16 bf16x8_t __attribute__((ext_vector_type(8)));
typedef __bf16 bf16x4_t __attribute__((ext_vector_type(4)));
typedef float f32x4  __attribute__((ext_vector_type(4)));
typedef float f32x16 __attribute__((ext_vector_type(16)));

#define AS1 __attribute__((address_space(1)))
#define AS3 __attribute__((address_space(3)))

__device__ __forceinline__ void gll16(const void* g, void* l) {
  __builtin_amdgcn_global_load_lds((const AS1 void*)g, (AS3 void*)l, 16u, 0, 0u);
}

__device__ __forceinline__ __bf16 tobf(float f) {
  bf16 h = __float2bfloat16(f);
  return __builtin_bit_cast(__bf16, h);
}

// ---------------------------------------------------------------- cvt fp32->bf16
__global__ __launch_bounds__(256) void k_cvt(
    const float* __restrict__ x,  const float* __restrict__ wq,
    const float* __restrict__ wk, const float* __restrict__ wv,
    const float* __restrict__ wo,
    bf16* __restrict__ xb,  bf16* __restrict__ wqb, bf16* __restrict__ wkb,
    bf16* __restrict__ wvb, bf16* __restrict__ wob) {
  size_t id = (size_t)blockIdx.x * 256 + threadIdx.x;   // float4 units
  const float* s; bf16* d; size_t off;
  if (id < 2097152) { s = x; d = xb; off = id; }
  else {
    size_t r = id - 2097152;
    unsigned w = (unsigned)(r >> 20);
    off = r & 1048575u;
    s = (w == 0) ? wq : (w == 1) ? wk : (w == 2) ? wv : wo;
    d = (w == 0) ? wqb : (w == 1) ? wkb : (w == 2) ? wvb : wob;
  }
  const float4 v = ((const float4*)s)[off];
  bf16x4_t o = { tobf(v.x), tobf(v.y), tobf(v.z), tobf(v.w) };
  *(bf16x4_t*)(d + off * 4) = o;
}

// ---------------------------------------------------------------- lambda scalar
__global__ __launch_bounds__(256) void k_lam(
    const float* __restrict__ lq1, const float* __restrict__ lk1,
    const float* __restrict__ lq2, const float* __restrict__ lk2,
    float* __restrict__ lam) {
  __shared__ float r1[4], r2[4];
  int t = threadIdx.x;
  float a = lq1[t] * lk1[t];
  float b = lq2[t] * lk2[t];
#pragma unroll
  for (int s = 1; s < 64; s <<= 1) { a += __shfl_xor(a, s); b += __shfl_xor(b, s); }
  if ((t & 63) == 0) { r1[t >> 6] = a; r2[t >> 6] = b; }
  __syncthreads();
  if (t == 0) {
    float s1 = r1[0] + r1[1] + r1[2] + r1[3];
    float s2 = r2[0] + r2[1] + r2[2] + r2[3];
    *lam = expf(s1) - expf(s2) + 0.2f;
  }
}

// ================================================================ 256x256 8-phase
// m201-style schedule. 512 thr (8 waves 2Mx4N, per-wave 128x64), BK=64,
// LDS 128 KiB: [buf][half 128x64] per A,B, staged at half-tile granularity
// (2 gll16/thread per half). Per K-tile 4 phases = C-quadrants
// (lo,lo)->(lo,hi)->(hi,hi)->(hi,lo); per phase: {ds_read 12/4/8/0, stage one
// half, barrier, setprio+16 MFMA, barrier}; stage stagger A-hi(t+1)@ph1,
// A-lo(t+2)@ph2, B-lo(t+2)@ph3, B-hi(t+2)@ph4 -> vmcnt(6) once per tile.
// Col-frag map col=(cf&1)*64+(cf>>1)*128+n*16 keeps rotary pairs wave-local.
#define MFMA16(a, b, c) __builtin_amdgcn_mfma_f32_16x16x32_bf16(a, b, c, 0, 0, 0)

template<bool SWAP>
__device__ __forceinline__ void gemm256(
    const bf16* __restrict__ A, const bf16* __restrict__ B,
    int m0, int n0, bf16* lds, f32x4 (&acc)[8][4]) {
  const int tid = threadIdx.x, lane = tid & 63;
  const int wave = tid >> 6, m = wave >> 2, n = wave & 3;
  const int g = lane >> 4, l15 = lane & 15, l7 = lane & 7;

  const int sid0 = tid, sid1 = tid + 512;
  const int sr0 = sid0 >> 3, sc0 = (sid0 & 7) ^ (sr0 & 7);
  const int sr1 = sid1 >> 3, sc1 = (sid1 & 7) ^ (sr1 & 7);

  auto stageA = [&](int t, int h) {
    bf16* d = lds + ((size_t)((t & 1) * 2 + h)) * 8192;
    gll16(A + (size_t)(m0 + h * 128 + sr0) * 2048 + t * 64 + sc0 * 8, d + sid0 * 8);
    gll16(A + (size_t)(m0 + h * 128 + sr1) * 2048 + t * 64 + sc1 * 8, d + sid1 * 8);
  };
  auto stageB = [&](int t, int h) {
    bf16* d = lds + 32768 + ((size_t)((t & 1) * 2 + h)) * 8192;
    gll16(B + (size_t)(n0 + h * 128 + sr0) * 2048 + t * 64 + sc0 * 8, d + sid0 * 8);
    gll16(B + (size_t)(n0 + h * 128 + sr1) * 2048 + t * 64 + sc1 * 8, d + sid1 * 8);
  };

  // prologue: tile0 full + tile1 {A-lo,B-lo,B-hi}; 14 loads, keep newest 6.
  stageA(0, 0); stageB(0, 0); stageB(0, 1); stageA(0, 1);
  stageA(1, 0); stageB(1, 0); stageB(1, 1);
  asm volatile("s_waitcnt vmcnt(6)\n\ts_barrier" ::: "memory");

  for (int t = 0; t < 32; ++t) {
    const bf16* lA0 = lds + ((size_t)((t & 1) * 2 + 0)) * 8192;
    const bf16* lA1 = lds + ((size_t)((t & 1) * 2 + 1)) * 8192;
    const bf16* lB0 = lds + 32768 + ((size_t)((t & 1) * 2 + 0)) * 8192;
    const bf16* lB1 = lds + 32768 + ((size_t)((t & 1) * 2 + 1)) * 8192;
    bf16x8_t afl[4][2], afh[4][2], bvl[2][2], bvh[2][2];

    // -------- phase 1: (row-lo, col-lo). reads af-lo(8) + bv-lo(4)
#pragma unroll
    for (int ks = 0; ks < 2; ++ks) {
      const int pc = ((ks * 4 + g) ^ l7) * 8;
#pragma unroll
      for (int rf = 0; rf < 4; ++rf)
        afl[rf][ks] = *(const bf16x8_t*)(lA0 + (m * 64 + rf * 16 + l15) * 64 + pc);
#pragma unroll
      for (int cf = 0; cf < 2; ++cf)
        bvl[cf][ks] = *(const bf16x8_t*)(lB0 + (cf * 64 + n * 16 + l15) * 64 + pc);
    }
    if (t + 1 < 32) stageA(t + 1, 1);                 // A-hi(t+1)
    asm volatile("s_barrier" ::: "memory");
    __builtin_amdgcn_s_setprio(1);
#pragma unroll
    for (int ks = 0; ks < 2; ++ks)
#pragma unroll
      for (int rf = 0; rf < 4; ++rf)
#pragma unroll
        for (int cf = 0; cf < 2; ++cf)
          acc[rf][cf] = SWAP ? MFMA16(bvl[cf][ks], afl[rf][ks], acc[rf][cf])
                             : MFMA16(afl[rf][ks], bvl[cf][ks], acc[rf][cf]);
    __builtin_amdgcn_s_setprio(0);
    asm volatile("s_barrier" ::: "memory");

    // -------- phase 2: (row-lo, col-hi). reads bv-hi(4)
#pragma unroll
    for (int ks = 0; ks < 2; ++ks) {
      const int pc = ((ks * 4 + g) ^ l7) * 8;
#pragma unroll
      for (int cf = 0; cf < 2; ++cf)
        bvh[cf][ks] = *(const bf16x8_t*)(lB1 + (cf * 64 + n * 16 + l15) * 64 + pc);
    }
    if (t + 2 < 32) stageA(t + 2, 0);                 // A-lo(t+2)
    asm volatile("s_barrier" ::: "memory");
    __builtin_amdgcn_s_setprio(1);
#pragma unroll
    for (int ks = 0; ks < 2; ++ks)
#pragma unroll
      for (int rf = 0; rf < 4; ++rf)
#pragma unroll
        for (int cf = 0; cf < 2; ++cf)
          acc[rf][cf + 2] = SWAP ? MFMA16(bvh[cf][ks], afl[rf][ks], acc[rf][cf + 2])
                                 : MFMA16(afl[rf][ks], bvh[cf][ks], acc[rf][cf + 2]);
    __builtin_amdgcn_s_setprio(0);
    asm volatile("s_barrier" ::: "memory");

    // -------- phase 3: (row-hi, col-hi). reads af-hi(8)
#pragma unroll
    for (int ks = 0; ks < 2; ++ks) {
      const int pc = ((ks * 4 + g) ^ l7) * 8;
#pragma unroll
      for (int rf = 0; rf < 4; ++rf)
        afh[rf][ks] = *(const bf16x8_t*)(lA1 + (m * 64 + rf * 16 + l15) * 64 + pc);
    }
    if (t + 2 < 32) stageB(t + 2, 0);                 // B-lo(t+2)
    asm volatile("s_barrier" ::: "memory");
    __builtin_amdgcn_s_setprio(1);
#pragma unroll
    for (int ks = 0; ks < 2; ++ks)
#pragma unroll
      for (int rf = 0; rf < 4; ++rf)
#pragma unroll
        for (int cf = 0; cf < 2; ++cf)
          acc[rf + 4][cf + 2] = SWAP ? MFMA16(bvh[cf][ks], afh[rf][ks], acc[rf + 4][cf + 2])
                                     : MFMA16(afh[rf][ks], bvh[cf][ks], acc[rf + 4][cf + 2]);
    __builtin_amdgcn_s_setprio(0);
    asm volatile("s_barrier" ::: "memory");

    // -------- phase 4: (row-hi, col-lo). no reads (afh, bvl in regs)
    if (t + 2 < 32) stageB(t + 2, 1);                 // B-hi(t+2)
    asm volatile("s_barrier" ::: "memory");
    __builtin_amdgcn_s_setprio(1);
#pragma unroll
    for (int ks = 0; ks < 2; ++ks)
#pragma unroll
      for (int rf = 0; rf < 4; ++rf)
#pragma unroll
        for (int cf = 0; cf < 2; ++cf)
          acc[rf + 4][cf] = SWAP ? MFMA16(bvl[cf][ks], afh[rf][ks], acc[rf + 4][cf])
                                 : MFMA16(afh[rf][ks], bvl[cf][ks], acc[rf + 4][cf]);
    __builtin_amdgcn_s_setprio(0);
    // tile boundary: all of t+1 landed; newest 6 loads = {A-lo,B-lo,B-hi}(t+2)
    if (t < 30)      asm volatile("s_waitcnt vmcnt(6)\n\ts_barrier" ::: "memory");
    else             asm volatile("s_waitcnt vmcnt(0)\n\ts_barrier" ::: "memory");
  }
}

// ---------------------------------------------------------------- QKV projection
__global__ __launch_bounds__(512, 2) void k_gemm_qkv(
    const bf16* __restrict__ xb,
    const bf16* __restrict__ wqb, const bf16* __restrict__ wkb,
    const bf16* __restrict__ wvb,
    bf16* __restrict__ q1, bf16* __restrict__ q2,
    bf16* __restrict__ k1, bf16* __restrict__ k2,
    bf16* __restrict__ vt) {
  __shared__ __align__(16) bf16 lds[65536];           // 128 KiB GEMM tiles
  __shared__ float exs[2][4][256];                    // 8 KiB rms exchange
  __shared__ float lCs[64], lSn[64];
  const int z  = blockIdx.z;
  const int m0 = blockIdx.y * 256, n0 = blockIdx.x * 256;
  const int nh = blockIdx.x;                          // BN=256 == one head
  const int tid = threadIdx.x, lane = tid & 63, wave = tid >> 6;
  const int m = wave >> 2, n = wave & 3;
  const int g = lane >> 4, l15 = lane & 15;
  f32x4 acc[8][4] = {};

  if (z < 2) {
    if (tid < 64) {
      float fr = exp2f(-(float)tid * 0.20762050593045951f);  // log2(10000)/64
      float sn, cs;
      sincosf((float)nh * fr, &sn, &cs);
      lCs[tid] = cs; lSn[tid] = sn;
    }
    const bf16* Bm = z ? wkb : wqb;
    gemm256<true>(xb, Bm, m0, n0, lds, acc);

    // rmsnorm partials: group0 = cf{0,1}, group1 = cf{2,3}; reduce over g,
    // then over the 4 n-waves via LDS.
#pragma unroll
    for (int rf = 0; rf < 8; ++rf) {
      float s0 = 0.f, s1 = 0.f;
#pragma unroll
      for (int r = 0; r < 4; ++r) {
        s0 += acc[rf][0][r] * acc[rf][0][r] + acc[rf][1][r] * acc[rf][1][r];
        s1 += acc[rf][2][r] * acc[rf][2][r] + acc[rf][3][r] * acc[rf][3][r];
      }
      s0 += __shfl_xor(s0, 16); s0 += __shfl_xor(s0, 32);
      s1 += __shfl_xor(s1, 16); s1 += __shfl_xor(s1, 32);
      const int rrow = (rf >> 2) * 128 + m * 64 + (rf & 3) * 16 + l15;
      if (g == 0) { exs[0][n][rrow] = s0; exs[1][n][rrow] = s1; }
    }
    __syncthreads();
    bf16* dst1 = z ? k1 : q1;
    bf16* dst2 = z ? k2 : q2;
    const int j = n * 16 + 4 * g;
#pragma unroll
    for (int rf = 0; rf < 8; ++rf) {
      const int rrow = (rf >> 2) * 128 + m * 64 + (rf & 3) * 16 + l15;
      const float t0 = exs[0][0][rrow] + exs[0][1][rrow] + exs[0][2][rrow] + exs[0][3][rrow];
      const float t1 = exs[1][0][rrow] + exs[1][1][rrow] + exs[1][2][rrow] + exs[1][3][rrow];
      const float inv0 = rsqrtf(t0 * (1.0f / 128.0f) + 1.1920929e-07f);
      const float inv1 = rsqrtf(t1 * (1.0f / 128.0f) + 1.1920929e-07f);
      const size_t base = ((size_t)(m0 + rrow) * 8 + nh) * 128;
      bf16x4_t o1a, o2a, o1b, o2b;
#pragma unroll
      for (int r = 0; r < 4; ++r) {
        const float cs = lCs[j + r], sn = lSn[j + r];
        float x1 = acc[rf][0][r] * inv0, x2 = acc[rf][1][r] * inv0;
        o1a[r] = tobf(x1 * cs + x2 * sn);
        o2a[r] = tobf(x2 * cs - x1 * sn);
        x1 = acc[rf][2][r] * inv1; x2 = acc[rf][3][r] * inv1;
        o1b[r] = tobf(x1 * cs + x2 * sn);
        o2b[r] = tobf(x2 * cs - x1 * sn);
      }
      *(bf16x4_t*)(dst1 + base + j)      = o1a;
      *(bf16x4_t*)(dst1 + base + j + 64) = o2a;
      *(bf16x4_t*)(dst2 + base + j)      = o1b;
      *(bf16x4_t*)(dst2 + base + j + 64) = o2b;
    }
  } else {
    gemm256<false>(xb, wvb, m0, n0, lds, acc);
    // V transposed to (bh, hd, t): unswapped reg-field = 4 consecutive rows
#pragma unroll
    for (int rf = 0; rf < 8; ++rf)
#pragma unroll
      for (int cf = 0; cf < 4; ++cf) {
        const int rb = m0 + (rf >> 2) * 128 + m * 64 + (rf & 3) * 16 + 4 * g;
        const int hd = (cf & 1) * 64 + (cf >> 1) * 128 + n * 16 + l15;
        const int b = rb >> 11, t = rb & 2047;
        bf16x4_t pv;
#pragma unroll
        for (int r = 0; r < 4; ++r) pv[r] = tobf(acc[rf][cf][r]);
        *(bf16x4_t*)(vt + ((size_t)((b * 8 + nh) * 256 + hd)) * 2048 + t) = pv;
      }
  }
}

// ---------------------------------------------------------------- GEMM core (NT)
// round-0 proven 128x128 core (2x2 wave tiling, 256 thr) for the output GEMM.
template<bool SWAP>
__device__ __forceinline__ void gemm_core(
    const bf16* __restrict__ A, const bf16* __restrict__ Bm,
    int m0, int n0, bf16* lA, bf16* lB, f32x4 (&acc)[4][4]) {
  const int tid  = threadIdx.x;
  const int lane = tid & 63;
  const int g    = lane >> 4;
  const int l15  = lane & 15;
  const int l7   = lane & 7;
  const int wave = tid >> 6;
  const int wm   = (wave >> 1) * 64;
  const int wn   = (wave & 1) * 64;

  int srow[4], ssc[4];
#pragma unroll
  for (int j = 0; j < 4; ++j) {
    int id = tid + j * 256;
    srow[j] = id >> 3;
    ssc[j]  = (id & 7) ^ (srow[j] & 7);
  }

  for (int k0 = 0; k0 < 2048; k0 += 64) {
    __syncthreads();
#pragma unroll
    for (int j = 0; j < 4; ++j) {
      int id = tid + j * 256;
      gll16(A  + (size_t)(m0 + srow[j]) * 2048 + k0 + ssc[j] * 8, lA + id * 8);
      gll16(Bm + (size_t)(n0 + srow[j]) * 2048 + k0 + ssc[j] * 8, lB + id * 8);
    }
    __syncthreads();
#pragma unroll
    for (int ks = 0; ks < 2; ++ks) {
      const int pc = (ks * 4 + g) ^ l7;
      bf16x8_t af[4], bfr[4];
#pragma unroll
      for (int mt = 0; mt < 4; ++mt)
        af[mt] = *(const bf16x8_t*)(lA + (wm + mt * 16 + l15) * 64 + pc * 8);
#pragma unroll
      for (int nt = 0; nt < 4; ++nt)
        bfr[nt] = *(const bf16x8_t*)(lB + (wn + nt * 16 + l15) * 64 + pc * 8);
#pragma unroll
      for (int mt = 0; mt < 4; ++mt)
#pragma unroll
        for (int nt = 0; nt < 4; ++nt) {
          if (SWAP)
            acc[mt][nt] = MFMA16(bfr[nt], af[mt], acc[mt][nt]);
          else
            acc[mt][nt] = MFMA16(af[mt], bfr[nt], acc[mt][nt]);
        }
    }
  }
}

// ---------------------------------------------------------------- output GEMM
__global__ __launch_bounds__(256) void k_gemm_out(
    const bf16* __restrict__ yb, const bf16* __restrict__ wob,
    float* __restrict__ outp) {
  __shared__ __align__(16) bf16 lA[128 * 64];
  __shared__ __align__(16) bf16 lB[128 * 64];
  const int m0 = blockIdx.y * 128, n0 = blockIdx.x * 128;
  f32x4 acc[4][4] = {};
  gemm_core<true>(yb, wob, m0, n0, lA, lB, acc);
  const int lane = threadIdx.x & 63, wave = threadIdx.x >> 6;
  const int g = lane >> 4, l15 = lane & 15;
  const int wm = (wave >> 1) * 64, wn = (wave & 1) * 64;
#pragma unroll
  for (int mt = 0; mt < 4; ++mt)
#pragma unroll
    for (int nt = 0; nt < 4; ++nt) {
      int row = m0 + wm + mt * 16 + l15;        // col-field = row (swapped)
      int col = n0 + wn + nt * 16 + 4 * g;      // reg-field = 4 consecutive cols
      f32x4 v;
#pragma unroll
      for (int r = 0; r < 4; ++r) v[r] = acc[mt][nt][r] * 0.8f;
      *(f32x4*)(outp + (size_t)row * 2048 + col) = v;
    }
}

// ---------------------------------------------------------------- flash attention
// 256 blocks (pair, bh): q-tiles qtB=31-pair then qtA=pair -> 33 k-iters each.
// Double-buffered K1/K2/V^T staging, one barrier per k-iter; P stays in regs
// (shfl_xor(32) C->B layout conversion).
__global__ __launch_bounds__(256, 1) void k_flash(
    const bf16* __restrict__ q1b, const bf16* __restrict__ q2b,
    const bf16* __restrict__ k1b, const bf16* __restrict__ k2b,
    const bf16* __restrict__ vtb, const float* __restrict__ lamp,
    bf16* __restrict__ yb) {
  __shared__ __align__(16) bf16 smem[65536];  // 128 KB
  const int tid  = threadIdx.x;
  const int lane = tid & 63, wave = tid >> 6;
  const int pair = blockIdx.x;           // 0..15
  const int bh = blockIdx.y;
  const int b = bh >> 3, nh = bh & 7;
  const int at = wave & 1, qg = wave >> 1;
  const int l31 = lane & 31, g5 = lane >> 5, l7 = lane & 7;
  const float scale = 0.08838834764831845f;  // 1/sqrt(128)
  const float lam = *lamp;

  auto stage = [&](int kt, int buf) {
    bf16* dst = smem + buf * 32768;
    const int k0 = kt * 64;
#pragma unroll
    for (int it = 0; it < 4; ++it) {
      int id = tid + it * 256;
      int row = id >> 4, c = id & 15;
      int sc = (c & 8) | ((c & 7) ^ (row & 7));
      size_t goff = ((size_t)(b * 2048 + k0 + row) * 8 + nh) * 128 + sc * 8;
      gll16(k1b + goff, dst + id * 8);
      gll16(k2b + goff, dst + 8192 + id * 8);
    }
#pragma unroll
    for (int it = 0; it < 8; ++it) {
      int id = tid + it * 256;
      int row = id >> 3, c = id & 7;
      int sc = c ^ (row & 7);
      gll16(vtb + ((size_t)(bh * 256 + row)) * 2048 + k0 + sc * 8,
            dst + 16384 + id * 8);
    }
  };

  bf16x8_t qf[8];
  auto loadQ = [&](int qt) {
    int qglob = qt * 64 + qg * 32 + l31;
    const bf16* qp = (at ? q2b : q1b) +
                     ((size_t)(b * 2048 + qglob) * 8 + nh) * 128 + g5 * 8;
#pragma unroll
    for (int ks = 0; ks < 8; ++ks) qf[ks] = *(const bf16x8_t*)(qp + ks * 16);
  };

  f32x16 O[8];
  float mrun, lrun;
  auto resetO = [&]() {
#pragma unroll
    for (int i = 0; i < 8; ++i)
#pragma unroll
      for (int j = 0; j < 16; ++j) O[i][j] = 0.f;
    mrun = -1e30f; lrun = 0.f;
  };

  auto step = [&](int kt, int buf, int qt) {
    const bf16* lk = smem + buf * 32768 + (at ? 8192 : 0);
    const bf16* lv = smem + buf * 32768 + 16384;
    const int k0 = kt * 64;
    const int qglob = qt * 64 + qg * 32 + l31;

    f32x16 s0, s1;
#pragma unroll
    for (int j = 0; j < 16; ++j) { s0[j] = 0.f; s1[j] = 0.f; }
#pragma unroll
    for (int ks = 0; ks < 8; ++ks) {
      int cl = ks * 2 + g5;
      int pc = (cl & 8) | ((cl & 7) ^ l7);
      bf16x8_t a0 = *(const bf16x8_t*)(lk + l31 * 128 + pc * 8);
      bf16x8_t a1 = *(const bf16x8_t*)(lk + (32 + l31) * 128 + pc * 8);
      s0 = __builtin_amdgcn_mfma_f32_32x32x16_bf16(a0, qf[ks], s0, 0, 0, 0);
      s1 = __builtin_amdgcn_mfma_f32_32x32x16_bf16(a1, qf[ks], s1, 0, 0, 0);
    }

    const bool diag = (kt == qt);
    float rmax = -3.0e38f;
#pragma unroll
    for (int r = 0; r < 16; ++r) {
      int key0 = k0 + (r & 3) + 8 * (r >> 2) + 4 * g5;
      float v0 = s0[r] * scale;
      float v1 = s1[r] * scale;
      if (diag) {
        if (key0 > qglob)      v0 = -1e30f;
        if (key0 + 32 > qglob) v1 = -1e30f;
      }
      s0[r] = v0; s1[r] = v1;
      rmax = fmaxf(rmax, fmaxf(v0, v1));
    }
    rmax = fmaxf(rmax, __shfl_xor(rmax, 32));
    float mnew = fmaxf(mrun, rmax);
    float alpha = __expf(mrun - mnew);
    float psum = 0.f;
#pragma unroll
    for (int r = 0; r < 16; ++r) {
      float p0 = __expf(s0[r] - mnew);
      float p1 = __expf(s1[r] - mnew);
      s0[r] = p0; s1[r] = p1;
      psum += p0 + p1;
    }
    psum += __shfl_xor(psum, 32);
    lrun = lrun * alpha + psum;
    mrun = mnew;
#pragma unroll
    for (int i = 0; i < 8; ++i) O[i] *= alpha;

#pragma unroll
    for (int sl = 0; sl < 4; ++sl) {
      const int h = sl & 1;
      bf16x4_t lo, hi;
#pragma unroll
      for (int j = 0; j < 4; ++j) {
        float vl = (sl < 2) ? s0[h * 8 + j]     : s1[h * 8 + j];
        float vh = (sl < 2) ? s0[h * 8 + 4 + j] : s1[h * 8 + 4 + j];
        lo[j] = tobf(vl); hi[j] = tobf(vh);
      }
      bf16x4_t send = g5 ? lo : hi;
      int2 si = __builtin_bit_cast(int2, send);
      int2 ri;
      ri.x = __shfl_xor(si.x, 32);
      ri.y = __shfl_xor(si.y, 32);
      bf16x4_t recv = __builtin_bit_cast(bf16x4_t, ri);
      bf16x4_t f0 = g5 ? recv : lo;
      bf16x4_t f1 = g5 ? hi : recv;
      bf16x8_t pf = { f0[0], f0[1], f0[2], f0[3], f1[0], f1[1], f1[2], f1[3] };

      const int cl = sl * 2 + g5;
#pragma unroll
      for (int mt = 0; mt < 8; ++mt) {
        bf16x8_t vf = *(const bf16x8_t*)(lv + (mt * 32 + l31) * 64 + (cl ^ l7) * 8);
        O[mt] = __builtin_amdgcn_mfma_f32_32x32x16_bf16(vf, pf, O[mt], 0, 0, 0);
      }
    }
  };

  auto finish = [&](int qt, bf16* cb) {
    const int qglob = qt * 64 + qg * 32 + l31;
    const float invl = 1.f / lrun;
    __syncthreads();
    if (at) {
      const float f = lam * invl;
#pragma unroll
      for (int mt = 0; mt < 8; ++mt)
#pragma unroll
        for (int rq = 0; rq < 4; ++rq) {
          int hd = mt * 32 + 8 * rq + 4 * g5;
          bf16x4_t pv;
#pragma unroll
          for (int i = 0; i < 4; ++i) pv[i] = tobf(O[mt][rq * 4 + i] * f);
          *(bf16x4_t*)(cb + (size_t)(qg * 32 + l31) * 264 + hd) = pv;
        }
    }
    __syncthreads();
    if (!at) {
#pragma unroll
      for (int mt = 0; mt < 8; ++mt)
#pragma unroll
        for (int rq = 0; rq < 4; ++rq) {
          int hd = mt * 32 + 8 * rq + 4 * g5;
          bf16x4_t o2 = *(const bf16x4_t*)(cb + (size_t)(qg * 32 + l31) * 264 + hd);
          bf16x4_t pv;
#pragma unroll
          for (int i = 0; i < 4; ++i)
            pv[i] = tobf(O[mt][rq * 4 + i] * invl - (float)o2[i]);
          *(bf16x4_t*)(yb + (size_t)(b * 2048 + qglob) * 2048 + nh * 256 + hd) = pv;
        }
    }
  };

  const int qtB = 31 - pair, qtA = pair;

  loadQ(qtB);
  resetO();
  stage(0, 0);
  for (int kt = 0; kt <= qtB; ++kt) {
    __syncthreads();
    if (kt < qtB) stage(kt + 1, (kt + 1) & 1);
    else          stage(0, (kt + 1) & 1);        // prefetch segment A kt=0
    step(kt, kt & 1, qtB);
  }
  finish(qtB, smem + (qtB & 1) * 32768);

  loadQ(qtA);
  resetO();
  for (int kt = 0; kt <= qtA; ++kt) {
    __syncthreads();
    if (kt < qtA) stage(kt + 1, (qtB + kt + 2) & 1);
    step(kt, (qtB + 1 + kt) & 1, qtA);
  }
  finish(qtA, smem + 32768);
}

// ---------------------------------------------------------------- launch
extern "C" void kernel_launch(void* const* d_in, const int* in_sizes, int n_in,
                              void* d_out, int out_size, void* d_ws, size_t ws_size,
                              hipStream_t stream) {
  (void)in_sizes; (void)n_in; (void)out_size; (void)ws_size;
  const float* x   = (const float*)d_in[0];
  const float* wq  = (const float*)d_in[1];
  const float* wk  = (const float*)d_in[2];
  const float* wv  = (const float*)d_in[3];
  const float* wo  = (const float*)d_in[4];
  const float* lq1 = (const float*)d_in[5];
  const float* lk1 = (const float*)d_in[6];
  const float* lq2 = (const float*)d_in[7];
  const float* lk2 = (const float*)d_in[8];
  float* out = (float*)d_out;

  char* p = (char*)d_ws;
  float* lam = (float*)p;            p += 256;
  bf16* xb  = (bf16*)p;              p += (size_t)4096 * 2048 * 2;
  bf16* wqb = (bf16*)p;              p += (size_t)2048 * 2048 * 2;
  bf16* wkb = (bf16*)p;              p += (size_t)2048 * 2048 * 2;
  bf16* wvb = (bf16*)p;              p += (size_t)2048 * 2048 * 2;
  bf16* wob = (bf16*)p;              p += (size_t)2048 * 2048 * 2;
  bf16* vt  = (bf16*)p;              p += (size_t)4096 * 2048 * 2;
  bf16* q1b = (bf16*)p;              p += (size_t)4096 * 1024 * 2;
  bf16* q2b = (bf16*)p;              p += (size_t)4096 * 1024 * 2;
  bf16* k1b = (bf16*)p;              p += (size_t)4096 * 1024 * 2;
  bf16* k2b = (bf16*)p;              p += (size_t)4096 * 1024 * 2;
  bf16* yb  = (bf16*)p;              p += (size_t)4096 * 2048 * 2;

  k_cvt<<<24576, 256, 0, stream>>>(x, wq, wk, wv, wo, xb, wqb, wkb, wvb, wob);
  k_lam<<<1, 256, 0, stream>>>(lq1, lk1, lq2, lk2, lam);
  k_gemm_qkv<<<dim3(8, 16, 3), 512, 0, stream>>>(xb, wqb, wkb, wvb,
                                                 q1b, q2b, k1b, k2b, vt);
  k_flash<<<dim3(16, 16), 256, 0, stream>>>(q1b, q2b, k1b, k2b, vt, lam, yb);
  k_gemm_out<<<dim3(16, 32), 256, 0, stream>>>(yb, wob, out);
}

// Round 3
// 425.716 us; speedup vs baseline: 1.0644x; 1.0194x over previous
//
#include <hip/hip_runtime.h>
#include <hip/hip_bf16.h>

using bf16 = __hip_bfloat16;
typedef __bf16 bf16x8_t __attribute__((ext_vector_type(8)));
typedef __bf16 bf16x4_t __attribute__((ext_vector_type(4)));
typedef float f32x4  __attribute__((ext_vector_type(4)));
typedef float f32x16 __attribute__((ext_vector_type(16)));

#define AS1 __attribute__((address_space(1)))
#define AS3 __attribute__((address_space(3)))

__device__ __forceinline__ void gll16(const void* g, void* l) {
  __builtin_amdgcn_global_load_lds((const AS1 void*)g, (AS3 void*)l, 16u, 0, 0u);
}

__device__ __forceinline__ __bf16 tobf(float f) {
  bf16 h = __float2bfloat16(f);
  return __builtin_bit_cast(__bf16, h);
}

// ---------------------------------------------------------------- cvt fp32->bf16
__global__ __launch_bounds__(256) void k_cvt(
    const float* __restrict__ x,  const float* __restrict__ wq,
    const float* __restrict__ wk, const float* __restrict__ wv,
    const float* __restrict__ wo,
    bf16* __restrict__ xb,  bf16* __restrict__ wqb, bf16* __restrict__ wkb,
    bf16* __restrict__ wvb, bf16* __restrict__ wob) {
  size_t id = (size_t)blockIdx.x * 256 + threadIdx.x;   // float4 units
  const float* s; bf16* d; size_t off;
  if (id < 2097152) { s = x; d = xb; off = id; }
  else {
    size_t r = id - 2097152;
    unsigned w = (unsigned)(r >> 20);
    off = r & 1048575u;
    s = (w == 0) ? wq : (w == 1) ? wk : (w == 2) ? wv : wo;
    d = (w == 0) ? wqb : (w == 1) ? wkb : (w == 2) ? wvb : wob;
  }
  const float4 v = ((const float4*)s)[off];
  bf16x4_t o = { tobf(v.x), tobf(v.y), tobf(v.z), tobf(v.w) };
  *(bf16x4_t*)(d + off * 4) = o;
}

// ---------------------------------------------------------------- lambda scalar
__global__ __launch_bounds__(256) void k_lam(
    const float* __restrict__ lq1, const float* __restrict__ lk1,
    const float* __restrict__ lq2, const float* __restrict__ lk2,
    float* __restrict__ lam) {
  __shared__ float r1[4], r2[4];
  int t = threadIdx.x;
  float a = lq1[t] * lk1[t];
  float b = lq2[t] * lk2[t];
#pragma unroll
  for (int s = 1; s < 64; s <<= 1) { a += __shfl_xor(a, s); b += __shfl_xor(b, s); }
  if ((t & 63) == 0) { r1[t >> 6] = a; r2[t >> 6] = b; }
  __syncthreads();
  if (t == 0) {
    float s1 = r1[0] + r1[1] + r1[2] + r1[3];
    float s2 = r2[0] + r2[1] + r2[2] + r2[3];
    *lam = expf(s1) - expf(s2) + 0.2f;
  }
}

// ================================================================ 256x256 8-phase
// m201-style schedule. 512 thr (8 waves 2Mx4N, per-wave 128x64), BK=64,
// LDS 128 KiB: [buf][half 128x64] per A,B, staged at half-tile granularity
// (2 gll16/thread per half). Per K-tile 4 phases = C-quadrants
// (lo,lo)->(lo,hi)->(hi,hi)->(hi,lo); per phase: {ds_read 12/4/8/0, stage one
// half, barrier, setprio+16 MFMA, barrier}; stage stagger A-hi(t+1)@ph1,
// A-lo(t+2)@ph2, B-lo(t+2)@ph3, B-hi(t+2)@ph4 -> vmcnt(6) once per tile.
// Col-frag map col=(cf&1)*64+(cf>>1)*128+n*16 keeps rotary pairs wave-local.
#define MFMA16(a, b, c) __builtin_amdgcn_mfma_f32_16x16x32_bf16(a, b, c, 0, 0, 0)

template<bool SWAP>
__device__ __forceinline__ void gemm256(
    const bf16* __restrict__ A, const bf16* __restrict__ B,
    int m0, int n0, bf16* lds, f32x4 (&acc)[8][4]) {
  const int tid = threadIdx.x, lane = tid & 63;
  const int wave = tid >> 6, m = wave >> 2, n = wave & 3;
  const int g = lane >> 4, l15 = lane & 15, l7 = lane & 7;

  const int sid0 = tid, sid1 = tid + 512;
  const int sr0 = sid0 >> 3, sc0 = (sid0 & 7) ^ (sr0 & 7);
  const int sr1 = sid1 >> 3, sc1 = (sid1 & 7) ^ (sr1 & 7);

  auto stageA = [&](int t, int h) {
    bf16* d = lds + ((size_t)((t & 1) * 2 + h)) * 8192;
    gll16(A + (size_t)(m0 + h * 128 + sr0) * 2048 + t * 64 + sc0 * 8, d + sid0 * 8);
    gll16(A + (size_t)(m0 + h * 128 + sr1) * 2048 + t * 64 + sc1 * 8, d + sid1 * 8);
  };
  auto stageB = [&](int t, int h) {
    bf16* d = lds + 32768 + ((size_t)((t & 1) * 2 + h)) * 8192;
    gll16(B + (size_t)(n0 + h * 128 + sr0) * 2048 + t * 64 + sc0 * 8, d + sid0 * 8);
    gll16(B + (size_t)(n0 + h * 128 + sr1) * 2048 + t * 64 + sc1 * 8, d + sid1 * 8);
  };

  // prologue: tile0 full + tile1 {A-lo,B-lo,B-hi}; 14 loads, keep newest 6.
  stageA(0, 0); stageB(0, 0); stageB(0, 1); stageA(0, 1);
  stageA(1, 0); stageB(1, 0); stageB(1, 1);
  asm volatile("s_waitcnt vmcnt(6)\n\ts_barrier" ::: "memory");

  for (int t = 0; t < 32; ++t) {
    const bf16* lA0 = lds + ((size_t)((t & 1) * 2 + 0)) * 8192;
    const bf16* lA1 = lds + ((size_t)((t & 1) * 2 + 1)) * 8192;
    const bf16* lB0 = lds + 32768 + ((size_t)((t & 1) * 2 + 0)) * 8192;
    const bf16* lB1 = lds + 32768 + ((size_t)((t & 1) * 2 + 1)) * 8192;
    bf16x8_t afl[4][2], afh[4][2], bvl[2][2], bvh[2][2];

    // -------- phase 1: (row-lo, col-lo). reads af-lo(8) + bv-lo(4)
#pragma unroll
    for (int ks = 0; ks < 2; ++ks) {
      const int pc = ((ks * 4 + g) ^ l7) * 8;
#pragma unroll
      for (int rf = 0; rf < 4; ++rf)
        afl[rf][ks] = *(const bf16x8_t*)(lA0 + (m * 64 + rf * 16 + l15) * 64 + pc);
#pragma unroll
      for (int cf = 0; cf < 2; ++cf)
        bvl[cf][ks] = *(const bf16x8_t*)(lB0 + (cf * 64 + n * 16 + l15) * 64 + pc);
    }
    if (t + 1 < 32) stageA(t + 1, 1);                 // A-hi(t+1)
    asm volatile("s_barrier" ::: "memory");
    __builtin_amdgcn_s_setprio(1);
#pragma unroll
    for (int ks = 0; ks < 2; ++ks)
#pragma unroll
      for (int rf = 0; rf < 4; ++rf)
#pragma unroll
        for (int cf = 0; cf < 2; ++cf)
          acc[rf][cf] = SWAP ? MFMA16(bvl[cf][ks], afl[rf][ks], acc[rf][cf])
                             : MFMA16(afl[rf][ks], bvl[cf][ks], acc[rf][cf]);
    __builtin_amdgcn_s_setprio(0);
    asm volatile("s_barrier" ::: "memory");

    // -------- phase 2: (row-lo, col-hi). reads bv-hi(4)
#pragma unroll
    for (int ks = 0; ks < 2; ++ks) {
      const int pc = ((ks * 4 + g) ^ l7) * 8;
#pragma unroll
      for (int cf = 0; cf < 2; ++cf)
        bvh[cf][ks] = *(const bf16x8_t*)(lB1 + (cf * 64 + n * 16 + l15) * 64 + pc);
    }
    if (t + 2 < 32) stageA(t + 2, 0);                 // A-lo(t+2)
    asm volatile("s_barrier" ::: "memory");
    __builtin_amdgcn_s_setprio(1);
#pragma unroll
    for (int ks = 0; ks < 2; ++ks)
#pragma unroll
      for (int rf = 0; rf < 4; ++rf)
#pragma unroll
        for (int cf = 0; cf < 2; ++cf)
          acc[rf][cf + 2] = SWAP ? MFMA16(bvh[cf][ks], afl[rf][ks], acc[rf][cf + 2])
                                 : MFMA16(afl[rf][ks], bvh[cf][ks], acc[rf][cf + 2]);
    __builtin_amdgcn_s_setprio(0);
    asm volatile("s_barrier" ::: "memory");

    // -------- phase 3: (row-hi, col-hi). reads af-hi(8)
#pragma unroll
    for (int ks = 0; ks < 2; ++ks) {
      const int pc = ((ks * 4 + g) ^ l7) * 8;
#pragma unroll
      for (int rf = 0; rf < 4; ++rf)
        afh[rf][ks] = *(const bf16x8_t*)(lA1 + (m * 64 + rf * 16 + l15) * 64 + pc);
    }
    if (t + 2 < 32) stageB(t + 2, 0);                 // B-lo(t+2)
    asm volatile("s_barrier" ::: "memory");
    __builtin_amdgcn_s_setprio(1);
#pragma unroll
    for (int ks = 0; ks < 2; ++ks)
#pragma unroll
      for (int rf = 0; rf < 4; ++rf)
#pragma unroll
        for (int cf = 0; cf < 2; ++cf)
          acc[rf + 4][cf + 2] = SWAP ? MFMA16(bvh[cf][ks], afh[rf][ks], acc[rf + 4][cf + 2])
                                     : MFMA16(afh[rf][ks], bvh[cf][ks], acc[rf + 4][cf + 2]);
    __builtin_amdgcn_s_setprio(0);
    asm volatile("s_barrier" ::: "memory");

    // -------- phase 4: (row-hi, col-lo). no reads (afh, bvl in regs)
    if (t + 2 < 32) stageB(t + 2, 1);                 // B-hi(t+2)
    asm volatile("s_barrier" ::: "memory");
    __builtin_amdgcn_s_setprio(1);
#pragma unroll
    for (int ks = 0; ks < 2; ++ks)
#pragma unroll
      for (int rf = 0; rf < 4; ++rf)
#pragma unroll
        for (int cf = 0; cf < 2; ++cf)
          acc[rf + 4][cf] = SWAP ? MFMA16(bvl[cf][ks], afh[rf][ks], acc[rf + 4][cf])
                                 : MFMA16(afh[rf][ks], bvl[cf][ks], acc[rf + 4][cf]);
    __builtin_amdgcn_s_setprio(0);
    // tile boundary: all of t+1 landed; newest 6 loads = {A-lo,B-lo,B-hi}(t+2)
    if (t < 30)      asm volatile("s_waitcnt vmcnt(6)\n\ts_barrier" ::: "memory");
    else             asm volatile("s_waitcnt vmcnt(0)\n\ts_barrier" ::: "memory");
  }
}

// ---------------------------------------------------------------- QKV projection
__global__ __launch_bounds__(512, 2) void k_gemm_qkv(
    const bf16* __restrict__ xb,
    const bf16* __restrict__ wqb, const bf16* __restrict__ wkb,
    const bf16* __restrict__ wvb,
    bf16* __restrict__ q1, bf16* __restrict__ q2,
    bf16* __restrict__ k1, bf16* __restrict__ k2,
    bf16* __restrict__ vt) {
  __shared__ __align__(16) bf16 lds[65536];           // 128 KiB GEMM tiles
  __shared__ float exs[2][4][256];                    // 8 KiB rms exchange
  __shared__ float lCs[64], lSn[64];
  const int z  = blockIdx.z;
  const int m0 = blockIdx.y * 256, n0 = blockIdx.x * 256;
  const int nh = blockIdx.x;                          // BN=256 == one head
  const int tid = threadIdx.x, lane = tid & 63, wave = tid >> 6;
  const int m = wave >> 2, n = wave & 3;
  const int g = lane >> 4, l15 = lane & 15;
  f32x4 acc[8][4] = {};

  if (z < 2) {
    if (tid < 64) {
      float fr = exp2f(-(float)tid * 0.20762050593045951f);  // log2(10000)/64
      float sn, cs;
      sincosf((float)nh * fr, &sn, &cs);
      lCs[tid] = cs; lSn[tid] = sn;
    }
    const bf16* Bm = z ? wkb : wqb;
    gemm256<true>(xb, Bm, m0, n0, lds, acc);

    // rmsnorm partials: group0 = cf{0,1}, group1 = cf{2,3}; reduce over g,
    // then over the 4 n-waves via LDS.
#pragma unroll
    for (int rf = 0; rf < 8; ++rf) {
      float s0 = 0.f, s1 = 0.f;
#pragma unroll
      for (int r = 0; r < 4; ++r) {
        s0 += acc[rf][0][r] * acc[rf][0][r] + acc[rf][1][r] * acc[rf][1][r];
        s1 += acc[rf][2][r] * acc[rf][2][r] + acc[rf][3][r] * acc[rf][3][r];
      }
      s0 += __shfl_xor(s0, 16); s0 += __shfl_xor(s0, 32);
      s1 += __shfl_xor(s1, 16); s1 += __shfl_xor(s1, 32);
      const int rrow = (rf >> 2) * 128 + m * 64 + (rf & 3) * 16 + l15;
      if (g == 0) { exs[0][n][rrow] = s0; exs[1][n][rrow] = s1; }
    }
    __syncthreads();
    bf16* dst1 = z ? k1 : q1;
    bf16* dst2 = z ? k2 : q2;
    const int j = n * 16 + 4 * g;
#pragma unroll
    for (int rf = 0; rf < 8; ++rf) {
      const int rrow = (rf >> 2) * 128 + m * 64 + (rf & 3) * 16 + l15;
      const float t0 = exs[0][0][rrow] + exs[0][1][rrow] + exs[0][2][rrow] + exs[0][3][rrow];
      const float t1 = exs[1][0][rrow] + exs[1][1][rrow] + exs[1][2][rrow] + exs[1][3][rrow];
      const float inv0 = rsqrtf(t0 * (1.0f / 128.0f) + 1.1920929e-07f);
      const float inv1 = rsqrtf(t1 * (1.0f / 128.0f) + 1.1920929e-07f);
      const size_t base = ((size_t)(m0 + rrow) * 8 + nh) * 128;
      bf16x4_t o1a, o2a, o1b, o2b;
#pragma unroll
      for (int r = 0; r < 4; ++r) {
        const float cs = lCs[j + r], sn = lSn[j + r];
        float x1 = acc[rf][0][r] * inv0, x2 = acc[rf][1][r] * inv0;
        o1a[r] = tobf(x1 * cs + x2 * sn);
        o2a[r] = tobf(x2 * cs - x1 * sn);
        x1 = acc[rf][2][r] * inv1; x2 = acc[rf][3][r] * inv1;
        o1b[r] = tobf(x1 * cs + x2 * sn);
        o2b[r] = tobf(x2 * cs - x1 * sn);
      }
      *(bf16x4_t*)(dst1 + base + j)      = o1a;
      *(bf16x4_t*)(dst1 + base + j + 64) = o2a;
      *(bf16x4_t*)(dst2 + base + j)      = o1b;
      *(bf16x4_t*)(dst2 + base + j + 64) = o2b;
    }
  } else {
    gemm256<false>(xb, wvb, m0, n0, lds, acc);
    // V transposed to (bh, hd, t): unswapped reg-field = 4 consecutive rows
#pragma unroll
    for (int rf = 0; rf < 8; ++rf)
#pragma unroll
      for (int cf = 0; cf < 4; ++cf) {
        const int rb = m0 + (rf >> 2) * 128 + m * 64 + (rf & 3) * 16 + 4 * g;
        const int hd = (cf & 1) * 64 + (cf >> 1) * 128 + n * 16 + l15;
        const int b = rb >> 11, t = rb & 2047;
        bf16x4_t pv;
#pragma unroll
        for (int r = 0; r < 4; ++r) pv[r] = tobf(acc[rf][cf][r]);
        *(bf16x4_t*)(vt + ((size_t)((b * 8 + nh) * 256 + hd)) * 2048 + t) = pv;
      }
  }
}

// ---------------------------------------------------------------- GEMM core (NT)
// round-0 proven 128x128 core (2x2 wave tiling, 256 thr) for the output GEMM.
template<bool SWAP>
__device__ __forceinline__ void gemm_core(
    const bf16* __restrict__ A, const bf16* __restrict__ Bm,
    int m0, int n0, bf16* lA, bf16* lB, f32x4 (&acc)[4][4]) {
  const int tid  = threadIdx.x;
  const int lane = tid & 63;
  const int g    = lane >> 4;
  const int l15  = lane & 15;
  const int l7   = lane & 7;
  const int wave = tid >> 6;
  const int wm   = (wave >> 1) * 64;
  const int wn   = (wave & 1) * 64;

  int srow[4], ssc[4];
#pragma unroll
  for (int j = 0; j < 4; ++j) {
    int id = tid + j * 256;
    srow[j] = id >> 3;
    ssc[j]  = (id & 7) ^ (srow[j] & 7);
  }

  for (int k0 = 0; k0 < 2048; k0 += 64) {
    __syncthreads();
#pragma unroll
    for (int j = 0; j < 4; ++j) {
      int id = tid + j * 256;
      gll16(A  + (size_t)(m0 + srow[j]) * 2048 + k0 + ssc[j] * 8, lA + id * 8);
      gll16(Bm + (size_t)(n0 + srow[j]) * 2048 + k0 + ssc[j] * 8, lB + id * 8);
    }
    __syncthreads();
#pragma unroll
    for (int ks = 0; ks < 2; ++ks) {
      const int pc = (ks * 4 + g) ^ l7;
      bf16x8_t af[4], bfr[4];
#pragma unroll
      for (int mt = 0; mt < 4; ++mt)
        af[mt] = *(const bf16x8_t*)(lA + (wm + mt * 16 + l15) * 64 + pc * 8);
#pragma unroll
      for (int nt = 0; nt < 4; ++nt)
        bfr[nt] = *(const bf16x8_t*)(lB + (wn + nt * 16 + l15) * 64 + pc * 8);
#pragma unroll
      for (int mt = 0; mt < 4; ++mt)
#pragma unroll
        for (int nt = 0; nt < 4; ++nt) {
          if (SWAP)
            acc[mt][nt] = MFMA16(bfr[nt], af[mt], acc[mt][nt]);
          else
            acc[mt][nt] = MFMA16(af[mt], bfr[nt], acc[mt][nt]);
        }
    }
  }
}

// ---------------------------------------------------------------- output GEMM
__global__ __launch_bounds__(256) void k_gemm_out(
    const bf16* __restrict__ yb, const bf16* __restrict__ wob,
    float* __restrict__ outp) {
  __shared__ __align__(16) bf16 lA[128 * 64];
  __shared__ __align__(16) bf16 lB[128 * 64];
  const int m0 = blockIdx.y * 128, n0 = blockIdx.x * 128;
  f32x4 acc[4][4] = {};
  gemm_core<true>(yb, wob, m0, n0, lA, lB, acc);
  const int lane = threadIdx.x & 63, wave = threadIdx.x >> 6;
  const int g = lane >> 4, l15 = lane & 15;
  const int wm = (wave >> 1) * 64, wn = (wave & 1) * 64;
#pragma unroll
  for (int mt = 0; mt < 4; ++mt)
#pragma unroll
    for (int nt = 0; nt < 4; ++nt) {
      int row = m0 + wm + mt * 16 + l15;        // col-field = row (swapped)
      int col = n0 + wn + nt * 16 + 4 * g;      // reg-field = 4 consecutive cols
      f32x4 v;
#pragma unroll
      for (int r = 0; r < 4; ++r) v[r] = acc[mt][nt][r] * 0.8f;
      *(f32x4*)(outp + (size_t)row * 2048 + col) = v;
    }
}

// ---------------------------------------------------------------- flash attention
// 256 blocks (pair, bh) x 512 thr (8 waves = at x qg x kvh). kv-split flash:
// waves kvh=0/1 handle keys [0,32)/[32,64) of each staged 64-key step with
// independent online-softmax states (flash-decode split), combined in f32 via
// the freed LDS buffer at finish (combine weight exp2(m_i - m*) zeroes the
// empty-half case automatically). 2 waves/SIMD fill each other's latency.
// Defer-max (log2-THR=8) skips most O-rescales; scale*log2e folded into the
// S scaling so softmax uses raw exp2.
__global__ __launch_bounds__(512, 2) void k_flash(
    const bf16* __restrict__ q1b, const bf16* __restrict__ q2b,
    const bf16* __restrict__ k1b, const bf16* __restrict__ k2b,
    const bf16* __restrict__ vtb, const float* __restrict__ lamp,
    bf16* __restrict__ yb) {
  __shared__ __align__(16) bf16 smem[65536];  // 128 KB
  __shared__ float mx[8][32], lx[8][32];
  const int tid  = threadIdx.x;
  const int lane = tid & 63, wave = tid >> 6;
  const int pair = blockIdx.x;           // 0..15
  const int bh = blockIdx.y;
  const int b = bh >> 3, nh = bh & 7;
  const int at = wave & 1, qg = (wave >> 1) & 1, kvh = wave >> 2;
  const int l31 = lane & 31, g5 = lane >> 5, l7 = lane & 7;
  const float sl2e = 0.12751743f;        // (1/sqrt(128)) * log2(e)
  const float lam = *lamp;

  auto stage = [&](int kt, int buf) {
    bf16* dst = smem + buf * 32768;
    const int k0 = kt * 64;
#pragma unroll
    for (int it = 0; it < 2; ++it) {
      int id = tid + it * 512;
      int row = id >> 4, c = id & 15;
      int sc = (c & 8) | ((c & 7) ^ (row & 7));
      size_t goff = ((size_t)(b * 2048 + k0 + row) * 8 + nh) * 128 + sc * 8;
      gll16(k1b + goff, dst + id * 8);
      gll16(k2b + goff, dst + 8192 + id * 8);
    }
#pragma unroll
    for (int it = 0; it < 4; ++it) {
      int id = tid + it * 512;
      int row = id >> 3, c = id & 7;
      int sc = c ^ (row & 7);
      gll16(vtb + ((size_t)(bh * 256 + row)) * 2048 + k0 + sc * 8,
            dst + 16384 + id * 8);
    }
  };

  bf16x8_t qf[8];
  auto loadQ = [&](int qt) {
    int qglob = qt * 64 + qg * 32 + l31;
    const bf16* qp = (at ? q2b : q1b) +
                     ((size_t)(b * 2048 + qglob) * 8 + nh) * 128 + g5 * 8;
#pragma unroll
    for (int ks = 0; ks < 8; ++ks) qf[ks] = *(const bf16x8_t*)(qp + ks * 16);
  };

  f32x16 O[8];
  float mrun, lrun;
  auto resetO = [&]() {
#pragma unroll
    for (int i = 0; i < 8; ++i)
#pragma unroll
      for (int j = 0; j < 16; ++j) O[i][j] = 0.f;
    mrun = -1e30f; lrun = 0.f;
  };

  auto step = [&](int kt, int buf, int qt) {
    const int k0 = kt * 64 + kvh * 32;
    if (k0 > qt * 64 + qg * 32 + 31) return;   // all keys causal-masked
    const bf16* lk = smem + buf * 32768 + (at ? 8192 : 0);
    const bf16* lv = smem + buf * 32768 + 16384;
    const int qglob = qt * 64 + qg * 32 + l31;

    f32x16 s0;
#pragma unroll
    for (int j = 0; j < 16; ++j) s0[j] = 0.f;
#pragma unroll
    for (int ks = 0; ks < 8; ++ks) {
      int cl = ks * 2 + g5;
      int pc = (cl & 8) | ((cl & 7) ^ l7);
      bf16x8_t a0 = *(const bf16x8_t*)(lk + (kvh * 32 + l31) * 128 + pc * 8);
      s0 = __builtin_amdgcn_mfma_f32_32x32x16_bf16(a0, qf[ks], s0, 0, 0, 0);
    }

    const bool needmask = (k0 + 31 > qt * 64 + qg * 32);
    float rmax = -3.0e38f;
#pragma unroll
    for (int r = 0; r < 16; ++r) {
      float v0 = s0[r] * sl2e;                 // log2-domain scores
      if (needmask) {
        int key0 = k0 + (r & 3) + 8 * (r >> 2) + 4 * g5;
        if (key0 > qglob) v0 = -1e30f;
      }
      s0[r] = v0;
      rmax = fmaxf(rmax, v0);
    }
    rmax = fmaxf(rmax, __shfl_xor(rmax, 32));
    if (!__all(rmax - mrun <= 8.0f)) {         // defer-max: P bounded by 2^8
      float mnew = fmaxf(mrun, rmax);
      float alpha = exp2f(mrun - mnew);
      lrun *= alpha;
#pragma unroll
      for (int i = 0; i < 8; ++i) O[i] *= alpha;
      mrun = mnew;
    }
    float psum = 0.f;
#pragma unroll
    for (int r = 0; r < 16; ++r) {
      float p0 = exp2f(s0[r] - mrun);
      s0[r] = p0;
      psum += p0;
    }
    psum += __shfl_xor(psum, 32);
    lrun += psum;

#pragma unroll
    for (int sl = 0; sl < 2; ++sl) {
      bf16x4_t lo, hi;
#pragma unroll
      for (int j = 0; j < 4; ++j) {
        lo[j] = tobf(s0[sl * 8 + j]);
        hi[j] = tobf(s0[sl * 8 + 4 + j]);
      }
      bf16x4_t send = g5 ? lo : hi;
      int2 si = __builtin_bit_cast(int2, send);
      int2 ri;
      ri.x = __shfl_xor(si.x, 32);
      ri.y = __shfl_xor(si.y, 32);
      bf16x4_t recv = __builtin_bit_cast(bf16x4_t, ri);
      bf16x4_t f0 = g5 ? recv : lo;
      bf16x4_t f1 = g5 ? hi : recv;
      bf16x8_t pf = { f0[0], f0[1], f0[2], f0[3], f1[0], f1[1], f1[2], f1[3] };

      const int cl = kvh * 4 + sl * 2 + g5;
#pragma unroll
      for (int mt = 0; mt < 8; ++mt) {
        bf16x8_t vf = *(const bf16x8_t*)(lv + (mt * 32 + l31) * 64 + (cl ^ l7) * 8);
        O[mt] = __builtin_amdgcn_mfma_f32_32x32x16_bf16(vf, pf, O[mt], 0, 0, 0);
      }
    }
  };

  auto finish = [&](int qt, bf16* cbuf) {
    const int qglob = qt * 64 + qg * 32 + l31;
    float* XF = (float*)cbuf;                  // 64 KB = 16384 f32, free buffer
    __syncthreads();                           // all waves done reading cbuf
    if (g5 == 0) { mx[wave][l31] = mrun; lx[wave][l31] = lrun; }
    __syncthreads();
    const float mo  = mx[wave ^ 4][l31];
    const float lo2 = lx[wave ^ 4][l31];
    const float ms = fmaxf(mrun, mo);
    const float ws = exp2f(mrun - ms);         // own weight (0 if state empty)
    const float wo = exp2f(mo - ms);
    const float lstar = lrun * ws + lo2 * wo;
    // two rounds of f32 O-combine (64 KB holds 2 waves' O at a time)
#pragma unroll
    for (int rnd = 0; rnd < 2; ++rnd) {
      if (at == rnd && kvh == 1) {
#pragma unroll
        for (int mt = 0; mt < 8; ++mt)
#pragma unroll
          for (int rq = 0; rq < 4; ++rq) {
            int hd = mt * 32 + 8 * rq + 4 * g5;
            f32x4 v;
#pragma unroll
            for (int i = 0; i < 4; ++i) v[i] = O[mt][rq * 4 + i] * ws;
            *(f32x4*)(XF + qg * 8192 + l31 * 256 + hd) = v;
          }
      }
      __syncthreads();
      if (at == rnd && kvh == 0) {
#pragma unroll
        for (int mt = 0; mt < 8; ++mt)
#pragma unroll
          for (int rq = 0; rq < 4; ++rq) {
            int hd = mt * 32 + 8 * rq + 4 * g5;
            f32x4 v = *(const f32x4*)(XF + qg * 8192 + l31 * 256 + hd);
#pragma unroll
            for (int i = 0; i < 4; ++i)
              O[mt][rq * 4 + i] = O[mt][rq * 4 + i] * ws + v[i];
          }
      }
      __syncthreads();
    }
    // branch subtraction among kvh=0 waves (cbuf reusable as bf16 now)
    const float invl = 1.f / lstar;
    if (kvh == 0 && at == 1) {
      const float f = lam * invl;
#pragma unroll
      for (int mt = 0; mt < 8; ++mt)
#pragma unroll
        for (int rq = 0; rq < 4; ++rq) {
          int hd = mt * 32 + 8 * rq + 4 * g5;
          bf16x4_t pv;
#pragma unroll
          for (int i = 0; i < 4; ++i) pv[i] = tobf(O[mt][rq * 4 + i] * f);
          *(bf16x4_t*)(cbuf + (size_t)(qg * 32 + l31) * 264 + hd) = pv;
        }
    }
    __syncthreads();
    if (kvh == 0 && at == 0) {
#pragma unroll
      for (int mt = 0; mt < 8; ++mt)
#pragma unroll
        for (int rq = 0; rq < 4; ++rq) {
          int hd = mt * 32 + 8 * rq + 4 * g5;
          bf16x4_t o2 = *(const bf16x4_t*)(cbuf + (size_t)(qg * 32 + l31) * 264 + hd);
          bf16x4_t pv;
#pragma unroll
          for (int i = 0; i < 4; ++i)
            pv[i] = tobf(O[mt][rq * 4 + i] * invl - (float)o2[i]);
          *(bf16x4_t*)(yb + (size_t)(b * 2048 + qglob) * 2048 + nh * 256 + hd) = pv;
        }
    }
  };

  const int qtB = 31 - pair, qtA = pair;

  loadQ(qtB);
  resetO();
  stage(0, 0);
  for (int kt = 0; kt <= qtB; ++kt) {
    __syncthreads();
    if (kt < qtB) stage(kt + 1, (kt + 1) & 1);
    else          stage(0, (kt + 1) & 1);        // prefetch segment A kt=0
    step(kt, kt & 1, qtB);
  }
  finish(qtB, smem + (qtB & 1) * 32768);

  loadQ(qtA);
  resetO();
  for (int kt = 0; kt <= qtA; ++kt) {
    __syncthreads();
    if (kt < qtA) stage(kt + 1, (qtB + kt + 2) & 1);
    step(kt, (qtB + 1 + kt) & 1, qtA);
  }
  finish(qtA, smem + 32768);
}

// ---------------------------------------------------------------- launch
extern "C" void kernel_launch(void* const* d_in, const int* in_sizes, int n_in,
                              void* d_out, int out_size, void* d_ws, size_t ws_size,
                              hipStream_t stream) {
  (void)in_sizes; (void)n_in; (void)out_size; (void)ws_size;
  const float* x   = (const float*)d_in[0];
  const float* wq  = (const float*)d_in[1];
  const float* wk  = (const float*)d_in[2];
  const float* wv  = (const float*)d_in[3];
  const float* wo  = (const float*)d_in[4];
  const float* lq1 = (const float*)d_in[5];
  const float* lk1 = (const float*)d_in[6];
  const float* lq2 = (const float*)d_in[7];
  const float* lk2 = (const float*)d_in[8];
  float* out = (float*)d_out;

  char* p = (char*)d_ws;
  float* lam = (float*)p;            p += 256;
  bf16* xb  = (bf16*)p;              p += (size_t)4096 * 2048 * 2;
  bf16* wqb = (bf16*)p;              p += (size_t)2048 * 2048 * 2;
  bf16* wkb = (bf16*)p;              p += (size_t)2048 * 2048 * 2;
  bf16* wvb = (bf16*)p;              p += (size_t)2048 * 2048 * 2;
  bf16* wob = (bf16*)p;              p += (size_t)2048 * 2048 * 2;
  bf16* vt  = (bf16*)p;              p += (size_t)4096 * 2048 * 2;
  bf16* q1b = (bf16*)p;              p += (size_t)4096 * 1024 * 2;
  bf16* q2b = (bf16*)p;              p += (size_t)4096 * 1024 * 2;
  bf16* k1b = (bf16*)p;              p += (size_t)4096 * 1024 * 2;
  bf16* k2b = (bf16*)p;              p += (size_t)4096 * 1024 * 2;
  bf16* yb  = (bf16*)p;              p += (size_t)4096 * 2048 * 2;

  k_cvt<<<24576, 256, 0, stream>>>(x, wq, wk, wv, wo, xb, wqb, wkb, wvb, wob);
  k_lam<<<1, 256, 0, stream>>>(lq1, lk1, lq2, lk2, lam);
  k_gemm_qkv<<<dim3(8, 16, 3), 512, 0, stream>>>(xb, wqb, wkb, wvb,
                                                 q1b, q2b, k1b, k2b, vt);
  k_flash<<<dim3(16, 16), 512, 0, stream>>>(q1b, q2b, k1b, k2b, vt, lam, yb);
  k_gemm_out<<<dim3(16, 32), 256, 0, stream>>>(yb, wob, out);
}

// Round 4
// 417.976 us; speedup vs baseline: 1.0842x; 1.0185x over previous
//
#include <hip/hip_runtime.h>
#include <hip/hip_bf16.h>

using bf16 = __hip_bfloat16;
typedef __bf16 bf16x8_t __attribute__((ext_vector_type(8)));
typedef __bf16 bf16x4_t __attribute__((ext_vector_type(4)));
typedef float f32x4  __attribute__((ext_vector_type(4)));
typedef float f32x16 __attribute__((ext_vector_type(16)));

#define AS1 __attribute__((address_space(1)))
#define AS3 __attribute__((address_space(3)))

__device__ __forceinline__ void gll16(const void* g, void* l) {
  __builtin_amdgcn_global_load_lds((const AS1 void*)g, (AS3 void*)l, 16u, 0, 0u);
}

__device__ __forceinline__ __bf16 tobf(float f) {
  bf16 h = __float2bfloat16(f);
  return __builtin_bit_cast(__bf16, h);
}

// ---------------------------------------------------------------- cvt fp32->bf16 (+lam)
__global__ __launch_bounds__(256) void k_cvt(
    const float* __restrict__ x,  const float* __restrict__ wq,
    const float* __restrict__ wk, const float* __restrict__ wv,
    const float* __restrict__ wo,
    const float* __restrict__ lq1, const float* __restrict__ lk1,
    const float* __restrict__ lq2, const float* __restrict__ lk2,
    bf16* __restrict__ xb,  bf16* __restrict__ wqb, bf16* __restrict__ wkb,
    bf16* __restrict__ wvb, bf16* __restrict__ wob, float* __restrict__ lam) {
  if (blockIdx.x == 24576) {                 // fused lambda block
    __shared__ float r1[4], r2[4];
    int t = threadIdx.x;
    float a = lq1[t] * lk1[t];
    float b = lq2[t] * lk2[t];
#pragma unroll
    for (int s = 1; s < 64; s <<= 1) { a += __shfl_xor(a, s); b += __shfl_xor(b, s); }
    if ((t & 63) == 0) { r1[t >> 6] = a; r2[t >> 6] = b; }
    __syncthreads();
    if (t == 0) {
      float s1 = r1[0] + r1[1] + r1[2] + r1[3];
      float s2 = r2[0] + r2[1] + r2[2] + r2[3];
      *lam = expf(s1) - expf(s2) + 0.2f;
    }
    return;
  }
  size_t id = (size_t)blockIdx.x * 256 + threadIdx.x;   // float4 units
  const float* s; bf16* d; size_t off;
  if (id < 2097152) { s = x; d = xb; off = id; }
  else {
    size_t r = id - 2097152;
    unsigned w = (unsigned)(r >> 20);
    off = r & 1048575u;
    s = (w == 0) ? wq : (w == 1) ? wk : (w == 2) ? wv : wo;
    d = (w == 0) ? wqb : (w == 1) ? wkb : (w == 2) ? wvb : wob;
  }
  const float4 v = ((const float4*)s)[off];
  bf16x4_t o = { tobf(v.x), tobf(v.y), tobf(v.z), tobf(v.w) };
  *(bf16x4_t*)(d + off * 4) = o;
}

// ================================================================ 256x128 2-phase GEMM
// 512 thr (8 waves 4Mx2N, per-wave 64x64), BK=64, ring-of-3 LDS slots
// (A 3x32KB + B 3x16KB = 144 KiB). Per K-tile: 2 phases, ONE barrier per
// phase (template-faithful): {reads, stage, barrier, [more reads], MFMA}.
// Phase-2 B-half reads issue after the ph1 barrier -> overlap MFMA1.
// Stage stagger: A(t+2)@ph1, B(t+2)@ph2; vmcnt(6) before ph2 barrier (the
// barrier makes all waves' per-wave vmcnt waits collectively visible) ->
// tile t+1 landed before its reads; never drains to 0 in steady state.
#define MFMA16(a, b, c) __builtin_amdgcn_mfma_f32_16x16x32_bf16(a, b, c, 0, 0, 0)

template<bool SWAP>
__device__ __forceinline__ void gemmKS(
    const bf16* __restrict__ A, const bf16* __restrict__ B,
    int m0, int n0, bf16* lA_, bf16* lB_, f32x4 (&acc)[4][4]) {
  const int tid = threadIdx.x, lane = tid & 63;
  const int wave = tid >> 6, m = wave >> 1, n = wave & 1;   // 4M x 2N
  const int g = lane >> 4, l15 = lane & 15, l7 = lane & 7;

  auto stageA = [&](int t, int sl) {
    bf16* d = lA_ + sl * 16384;
#pragma unroll
    for (int j = 0; j < 4; ++j) {
      int id = tid + j * 512;
      int row = id >> 3, sc = (id & 7) ^ (row & 7);
      gll16(A + (size_t)(m0 + row) * 2048 + t * 64 + sc * 8, d + id * 8);
    }
  };
  auto stageB = [&](int t, int sl) {
    bf16* d = lB_ + sl * 8192;
#pragma unroll
    for (int j = 0; j < 2; ++j) {
      int id = tid + j * 512;
      int row = id >> 3, sc = (id & 7) ^ (row & 7);
      gll16(B + (size_t)(n0 + row) * 2048 + t * 64 + sc * 8, d + id * 8);
    }
  };

  // prologue: tiles 0,1 in flight (12 loads); wait tile0 (keep newest 6)
  stageA(0, 0); stageB(0, 0); stageA(1, 1); stageB(1, 1);
  asm volatile("s_waitcnt vmcnt(6)\n\ts_barrier" ::: "memory");

  int s = 0;
  for (int t = 0; t < 32; ++t) {
    const bf16* la = lA_ + s * 16384;
    const bf16* lb = lB_ + s * 8192;
    int sp = s + 2; if (sp >= 3) sp -= 3;
    bf16x8_t af[4][2], bv[4][2];

    // ---- phase 1: read A(all rf) + B(cf0,1); stage A(t+2); barrier; MFMA1
#pragma unroll
    for (int ks = 0; ks < 2; ++ks) {
      const int pc = ((ks * 4 + g) ^ l7) * 8;
#pragma unroll
      for (int rf = 0; rf < 4; ++rf)
        af[rf][ks] = *(const bf16x8_t*)(la + (m * 64 + rf * 16 + l15) * 64 + pc);
#pragma unroll
      for (int cf = 0; cf < 2; ++cf)
        bv[cf][ks] = *(const bf16x8_t*)(lb + (n * 32 + cf * 16 + l15) * 64 + pc);
    }
    if (t + 2 < 32) stageA(t + 2, sp);
    asm volatile("s_barrier" ::: "memory");
    // B(cf2,3) reads issued now -> overlap MFMA1 on the LDS pipe
#pragma unroll
    for (int ks = 0; ks < 2; ++ks) {
      const int pc = ((ks * 4 + g) ^ l7) * 8;
#pragma unroll
      for (int cf = 0; cf < 2; ++cf)
        bv[cf + 2][ks] =
            *(const bf16x8_t*)(lb + (n * 32 + cf * 16 + 64 + l15) * 64 + pc);
    }
    __builtin_amdgcn_s_setprio(1);
#pragma unroll
    for (int ks = 0; ks < 2; ++ks)
#pragma unroll
      for (int rf = 0; rf < 4; ++rf)
#pragma unroll
        for (int cf = 0; cf < 2; ++cf)
          acc[rf][cf] = SWAP ? MFMA16(bv[cf][ks], af[rf][ks], acc[rf][cf])
                             : MFMA16(af[rf][ks], bv[cf][ks], acc[rf][cf]);
    __builtin_amdgcn_s_setprio(0);

    // ---- phase 2: stage B(t+2); vmcnt(6); barrier; MFMA2
    if (t + 2 < 32) {
      stageB(t + 2, sp);
      asm volatile("s_waitcnt vmcnt(6)" ::: "memory");  // tile t+1 landed
    } else if (t == 30) {
      asm volatile("s_waitcnt vmcnt(0)" ::: "memory");  // drain tile 31
    }
    asm volatile("s_barrier" ::: "memory");
    __builtin_amdgcn_s_setprio(1);
#pragma unroll
    for (int ks = 0; ks < 2; ++ks)
#pragma unroll
      for (int rf = 0; rf < 4; ++rf)
#pragma unroll
        for (int cf = 0; cf < 2; ++cf)
          acc[rf][cf + 2] = SWAP ? MFMA16(bv[cf + 2][ks], af[rf][ks], acc[rf][cf + 2])
                                 : MFMA16(af[rf][ks], bv[cf + 2][ks], acc[rf][cf + 2]);
    __builtin_amdgcn_s_setprio(0);
    s = (s == 2) ? 0 : s + 1;
  }
}

// ---------------------------------------------------------------- QKV projection
// grid (16,16,3) = 768 blocks = exactly 3 rounds at 1 block/CU.
// BN=128 == one rms-norm group; rotary pairs wave-local via
// col = n*32 + (cf&1)*16 + (cf>>1)*64.
__global__ __launch_bounds__(512, 2) void k_gemm_qkv(
    const bf16* __restrict__ xb,
    const bf16* __restrict__ wqb, const bf16* __restrict__ wkb,
    const bf16* __restrict__ wvb,
    bf16* __restrict__ q1, bf16* __restrict__ q2,
    bf16* __restrict__ k1, bf16* __restrict__ k2,
    bf16* __restrict__ vt) {
  __shared__ __align__(16) bf16 lA[3 * 16384];        // 96 KiB
  __shared__ __align__(16) bf16 lB[3 * 8192];         // 48 KiB
  __shared__ float exs[2][256];                       // 2 KiB rms exchange
  __shared__ float lCs[64], lSn[64];
  const int z  = blockIdx.z;
  const int m0 = blockIdx.y * 256, n0 = blockIdx.x * 128;
  const int nh = blockIdx.x >> 1, p = blockIdx.x & 1;
  const int tid = threadIdx.x, lane = tid & 63, wave = tid >> 6;
  const int m = wave >> 1, n = wave & 1;
  const int g = lane >> 4, l15 = lane & 15;
  f32x4 acc[4][4] = {};

  if (z < 2) {
    if (tid < 64) {
      float fr = exp2f(-(float)tid * 0.20762050593045951f);  // log2(10000)/64
      float sn, cs;
      sincosf((float)nh * fr, &sn, &cs);
      lCs[tid] = cs; lSn[tid] = sn;
    }
    const bf16* Bm = z ? wkb : wqb;
    gemmKS<true>(xb, Bm, m0, n0, lA, lB, acc);

    // rmsnorm: block's 128 cols = one group; reduce over g then 2 n-waves
    float ssr[4];
#pragma unroll
    for (int rf = 0; rf < 4; ++rf) {
      float ss = 0.f;
#pragma unroll
      for (int cf = 0; cf < 4; ++cf)
#pragma unroll
        for (int r = 0; r < 4; ++r) ss += acc[rf][cf][r] * acc[rf][cf][r];
      ss += __shfl_xor(ss, 16);
      ss += __shfl_xor(ss, 32);
      ssr[rf] = ss;
      if (g == 0) exs[n][m * 64 + rf * 16 + l15] = ss;
    }
    __syncthreads();
    bf16* dst = z ? (p ? k2 : k1) : (p ? q2 : q1);
#pragma unroll
    for (int rf = 0; rf < 4; ++rf) {
      const int rrow = m * 64 + rf * 16 + l15;
      const float tt = ssr[rf] + exs[n ^ 1][rrow];
      const float inv = rsqrtf(tt * (1.0f / 128.0f) + 1.1920929e-07f);
      const size_t base = ((size_t)(m0 + rrow) * 8 + nh) * 128;
#pragma unroll
      for (int cf = 0; cf < 2; ++cf) {
        const int jb = n * 32 + cf * 16 + 4 * g;
        bf16x4_t o1v, o2v;
#pragma unroll
        for (int r = 0; r < 4; ++r) {
          const float cs = lCs[jb + r], sn = lSn[jb + r];
          float x1 = acc[rf][cf][r] * inv;
          float x2 = acc[rf][cf + 2][r] * inv;
          o1v[r] = tobf(x1 * cs + x2 * sn);
          o2v[r] = tobf(x2 * cs - x1 * sn);
        }
        *(bf16x4_t*)(dst + base + jb)      = o1v;
        *(bf16x4_t*)(dst + base + jb + 64) = o2v;
      }
    }
  } else {
    gemmKS<false>(xb, wvb, m0, n0, lA, lB, acc);
    // V transposed to (bh, hd, t): unswapped reg-field = 4 consecutive rows
#pragma unroll
    for (int rf = 0; rf < 4; ++rf)
#pragma unroll
      for (int cf = 0; cf < 4; ++cf) {
        const int rb = m0 + m * 64 + rf * 16 + 4 * g;
        const int col = n0 + n * 32 + (cf & 1) * 16 + (cf >> 1) * 64 + l15;
        const int hd = col & 255;
        const int b = rb >> 11, t = rb & 2047;
        bf16x4_t pv;
#pragma unroll
        for (int r = 0; r < 4; ++r) pv[r] = tobf(acc[rf][cf][r]);
        *(bf16x4_t*)(vt + ((size_t)((b * 8 + nh) * 256 + hd)) * 2048 + t) = pv;
      }
  }
}

// ---------------------------------------------------------------- output GEMM
// grid (16,16) = 256 blocks = exactly 1 round.
__global__ __launch_bounds__(512, 2) void k_gemm_out(
    const bf16* __restrict__ yb, const bf16* __restrict__ wob,
    float* __restrict__ outp) {
  __shared__ __align__(16) bf16 lA[3 * 16384];
  __shared__ __align__(16) bf16 lB[3 * 8192];
  const int m0 = blockIdx.y * 256, n0 = blockIdx.x * 128;
  const int tid = threadIdx.x, lane = tid & 63, wave = tid >> 6;
  const int m = wave >> 1, n = wave & 1;
  const int g = lane >> 4, l15 = lane & 15;
  f32x4 acc[4][4] = {};
  gemmKS<true>(yb, wob, m0, n0, lA, lB, acc);
#pragma unroll
  for (int rf = 0; rf < 4; ++rf)
#pragma unroll
    for (int cf = 0; cf < 4; ++cf) {
      const int row = m0 + m * 64 + rf * 16 + l15;
      const int col = n0 + n * 32 + (cf & 1) * 16 + (cf >> 1) * 64 + 4 * g;
      f32x4 v;
#pragma unroll
      for (int r = 0; r < 4; ++r) v[r] = acc[rf][cf][r] * 0.8f;
      *(f32x4*)(outp + (size_t)row * 2048 + col) = v;
    }
}

// ---------------------------------------------------------------- flash attention
// 256 blocks (pair, bh) x 512 thr (8 waves = at x qg x kvh). kv-split flash:
// waves kvh=0/1 handle keys [0,32)/[32,64) of each staged 64-key step with
// independent online-softmax states, combined in f32 via the freed LDS buffer
// at finish. Defer-max (log2-THR=8); scale*log2e folded into S scaling.
__global__ __launch_bounds__(512, 2) void k_flash(
    const bf16* __restrict__ q1b, const bf16* __restrict__ q2b,
    const bf16* __restrict__ k1b, const bf16* __restrict__ k2b,
    const bf16* __restrict__ vtb, const float* __restrict__ lamp,
    bf16* __restrict__ yb) {
  __shared__ __align__(16) bf16 smem[65536];  // 128 KB
  __shared__ float mx[8][32], lx[8][32];
  const int tid  = threadIdx.x;
  const int lane = tid & 63, wave = tid >> 6;
  const int pair = blockIdx.x;           // 0..15
  const int bh = blockIdx.y;
  const int b = bh >> 3, nh = bh & 7;
  const int at = wave & 1, qg = (wave >> 1) & 1, kvh = wave >> 2;
  const int l31 = lane & 31, g5 = lane >> 5, l7 = lane & 7;
  const float sl2e = 0.12751743f;        // (1/sqrt(128)) * log2(e)
  const float lam = *lamp;

  auto stage = [&](int kt, int buf) {
    bf16* dst = smem + buf * 32768;
    const int k0 = kt * 64;
#pragma unroll
    for (int it = 0; it < 2; ++it) {
      int id = tid + it * 512;
      int row = id >> 4, c = id & 15;
      int sc = (c & 8) | ((c & 7) ^ (row & 7));
      size_t goff = ((size_t)(b * 2048 + k0 + row) * 8 + nh) * 128 + sc * 8;
      gll16(k1b + goff, dst + id * 8);
      gll16(k2b + goff, dst + 8192 + id * 8);
    }
#pragma unroll
    for (int it = 0; it < 4; ++it) {
      int id = tid + it * 512;
      int row = id >> 3, c = id & 7;
      int sc = c ^ (row & 7);
      gll16(vtb + ((size_t)(bh * 256 + row)) * 2048 + k0 + sc * 8,
            dst + 16384 + id * 8);
    }
  };

  bf16x8_t qf[8];
  auto loadQ = [&](int qt) {
    int qglob = qt * 64 + qg * 32 + l31;
    const bf16* qp = (at ? q2b : q1b) +
                     ((size_t)(b * 2048 + qglob) * 8 + nh) * 128 + g5 * 8;
#pragma unroll
    for (int ks = 0; ks < 8; ++ks) qf[ks] = *(const bf16x8_t*)(qp + ks * 16);
  };

  f32x16 O[8];
  float mrun, lrun;
  auto resetO = [&]() {
#pragma unroll
    for (int i = 0; i < 8; ++i)
#pragma unroll
      for (int j = 0; j < 16; ++j) O[i][j] = 0.f;
    mrun = -1e30f; lrun = 0.f;
  };

  auto step = [&](int kt, int buf, int qt) {
    const int k0 = kt * 64 + kvh * 32;
    if (k0 > qt * 64 + qg * 32 + 31) return;   // all keys causal-masked
    const bf16* lk = smem + buf * 32768 + (at ? 8192 : 0);
    const bf16* lv = smem + buf * 32768 + 16384;
    const int qglob = qt * 64 + qg * 32 + l31;

    f32x16 s0;
#pragma unroll
    for (int j = 0; j < 16; ++j) s0[j] = 0.f;
#pragma unroll
    for (int ks = 0; ks < 8; ++ks) {
      int cl = ks * 2 + g5;
      int pc = (cl & 8) | ((cl & 7) ^ l7);
      bf16x8_t a0 = *(const bf16x8_t*)(lk + (kvh * 32 + l31) * 128 + pc * 8);
      s0 = __builtin_amdgcn_mfma_f32_32x32x16_bf16(a0, qf[ks], s0, 0, 0, 0);
    }

    const bool needmask = (k0 + 31 > qt * 64 + qg * 32);
    float rmax = -3.0e38f;
#pragma unroll
    for (int r = 0; r < 16; ++r) {
      float v0 = s0[r] * sl2e;                 // log2-domain scores
      if (needmask) {
        int key0 = k0 + (r & 3) + 8 * (r >> 2) + 4 * g5;
        if (key0 > qglob) v0 = -1e30f;
      }
      s0[r] = v0;
      rmax = fmaxf(rmax, v0);
    }
    rmax = fmaxf(rmax, __shfl_xor(rmax, 32));
    if (!__all(rmax - mrun <= 8.0f)) {         // defer-max: P bounded by 2^8
      float mnew = fmaxf(mrun, rmax);
      float alpha = exp2f(mrun - mnew);
      lrun *= alpha;
#pragma unroll
      for (int i = 0; i < 8; ++i) O[i] *= alpha;
      mrun = mnew;
    }
    float psum = 0.f;
#pragma unroll
    for (int r = 0; r < 16; ++r) {
      float p0 = exp2f(s0[r] - mrun);
      s0[r] = p0;
      psum += p0;
    }
    psum += __shfl_xor(psum, 32);
    lrun += psum;

#pragma unroll
    for (int sl = 0; sl < 2; ++sl) {
      bf16x4_t lo, hi;
#pragma unroll
      for (int j = 0; j < 4; ++j) {
        lo[j] = tobf(s0[sl * 8 + j]);
        hi[j] = tobf(s0[sl * 8 + 4 + j]);
      }
      bf16x4_t send = g5 ? lo : hi;
      int2 si = __builtin_bit_cast(int2, send);
      int2 ri;
      ri.x = __shfl_xor(si.x, 32);
      ri.y = __shfl_xor(si.y, 32);
      bf16x4_t recv = __builtin_bit_cast(bf16x4_t, ri);
      bf16x4_t f0 = g5 ? recv : lo;
      bf16x4_t f1 = g5 ? hi : recv;
      bf16x8_t pf = { f0[0], f0[1], f0[2], f0[3], f1[0], f1[1], f1[2], f1[3] };

      const int cl = kvh * 4 + sl * 2 + g5;
#pragma unroll
      for (int mt = 0; mt < 8; ++mt) {
        bf16x8_t vf = *(const bf16x8_t*)(lv + (mt * 32 + l31) * 64 + (cl ^ l7) * 8);
        O[mt] = __builtin_amdgcn_mfma_f32_32x32x16_bf16(vf, pf, O[mt], 0, 0, 0);
      }
    }
  };

  auto finish = [&](int qt, bf16* cbuf) {
    const int qglob = qt * 64 + qg * 32 + l31;
    float* XF = (float*)cbuf;                  // 64 KB = 16384 f32, free buffer
    __syncthreads();                           // all waves done reading cbuf
    if (g5 == 0) { mx[wave][l31] = mrun; lx[wave][l31] = lrun; }
    __syncthreads();
    const float mo  = mx[wave ^ 4][l31];
    const float lo2 = lx[wave ^ 4][l31];
    const float ms = fmaxf(mrun, mo);
    const float ws = exp2f(mrun - ms);         // own weight (0 if state empty)
    const float wo = exp2f(mo - ms);
    const float lstar = lrun * ws + lo2 * wo;
    // two rounds of f32 O-combine (64 KB holds 2 waves' O at a time)
#pragma unroll
    for (int rnd = 0; rnd < 2; ++rnd) {
      if (at == rnd && kvh == 1) {
#pragma unroll
        for (int mt = 0; mt < 8; ++mt)
#pragma unroll
          for (int rq = 0; rq < 4; ++rq) {
            int hd = mt * 32 + 8 * rq + 4 * g5;
            f32x4 v;
#pragma unroll
            for (int i = 0; i < 4; ++i) v[i] = O[mt][rq * 4 + i] * ws;
            *(f32x4*)(XF + qg * 8192 + l31 * 256 + hd) = v;
          }
      }
      __syncthreads();
      if (at == rnd && kvh == 0) {
#pragma unroll
        for (int mt = 0; mt < 8; ++mt)
#pragma unroll
          for (int rq = 0; rq < 4; ++rq) {
            int hd = mt * 32 + 8 * rq + 4 * g5;
            f32x4 v = *(const f32x4*)(XF + qg * 8192 + l31 * 256 + hd);
#pragma unroll
            for (int i = 0; i < 4; ++i)
              O[mt][rq * 4 + i] = O[mt][rq * 4 + i] * ws + v[i];
          }
      }
      __syncthreads();
    }
    // branch subtraction among kvh=0 waves (cbuf reusable as bf16 now)
    const float invl = 1.f / lstar;
    if (kvh == 0 && at == 1) {
      const float f = lam * invl;
#pragma unroll
      for (int mt = 0; mt < 8; ++mt)
#pragma unroll
        for (int rq = 0; rq < 4; ++rq) {
          int hd = mt * 32 + 8 * rq + 4 * g5;
          bf16x4_t pv;
#pragma unroll
          for (int i = 0; i < 4; ++i) pv[i] = tobf(O[mt][rq * 4 + i] * f);
          *(bf16x4_t*)(cbuf + (size_t)(qg * 32 + l31) * 264 + hd) = pv;
        }
    }
    __syncthreads();
    if (kvh == 0 && at == 0) {
#pragma unroll
      for (int mt = 0; mt < 8; ++mt)
#pragma unroll
        for (int rq = 0; rq < 4; ++rq) {
          int hd = mt * 32 + 8 * rq + 4 * g5;
          bf16x4_t o2 = *(const bf16x4_t*)(cbuf + (size_t)(qg * 32 + l31) * 264 + hd);
          bf16x4_t pv;
#pragma unroll
          for (int i = 0; i < 4; ++i)
            pv[i] = tobf(O[mt][rq * 4 + i] * invl - (float)o2[i]);
          *(bf16x4_t*)(yb + (size_t)(b * 2048 + qglob) * 2048 + nh * 256 + hd) = pv;
        }
    }
  };

  const int qtB = 31 - pair, qtA = pair;

  loadQ(qtB);
  resetO();
  stage(0, 0);
  for (int kt = 0; kt <= qtB; ++kt) {
    __syncthreads();
    if (kt < qtB) stage(kt + 1, (kt + 1) & 1);
    else          stage(0, (kt + 1) & 1);        // prefetch segment A kt=0
    step(kt, kt & 1, qtB);
  }
  finish(qtB, smem + (qtB & 1) * 32768);

  loadQ(qtA);
  resetO();
  for (int kt = 0; kt <= qtA; ++kt) {
    __syncthreads();
    if (kt < qtA) stage(kt + 1, (qtB + kt + 2) & 1);
    step(kt, (qtB + 1 + kt) & 1, qtA);
  }
  finish(qtA, smem + 32768);
}

// ---------------------------------------------------------------- launch
extern "C" void kernel_launch(void* const* d_in, const int* in_sizes, int n_in,
                              void* d_out, int out_size, void* d_ws, size_t ws_size,
                              hipStream_t stream) {
  (void)in_sizes; (void)n_in; (void)out_size; (void)ws_size;
  const float* x   = (const float*)d_in[0];
  const float* wq  = (const float*)d_in[1];
  const float* wk  = (const float*)d_in[2];
  const float* wv  = (const float*)d_in[3];
  const float* wo  = (const float*)d_in[4];
  const float* lq1 = (const float*)d_in[5];
  const float* lk1 = (const float*)d_in[6];
  const float* lq2 = (const float*)d_in[7];
  const float* lk2 = (const float*)d_in[8];
  float* out = (float*)d_out;

  char* p = (char*)d_ws;
  float* lam = (float*)p;            p += 256;
  bf16* xb  = (bf16*)p;              p += (size_t)4096 * 2048 * 2;
  bf16* wqb = (bf16*)p;              p += (size_t)2048 * 2048 * 2;
  bf16* wkb = (bf16*)p;              p += (size_t)2048 * 2048 * 2;
  bf16* wvb = (bf16*)p;              p += (size_t)2048 * 2048 * 2;
  bf16* wob = (bf16*)p;              p += (size_t)2048 * 2048 * 2;
  bf16* vt  = (bf16*)p;              p += (size_t)4096 * 2048 * 2;
  bf16* q1b = (bf16*)p;              p += (size_t)4096 * 1024 * 2;
  bf16* q2b = (bf16*)p;              p += (size_t)4096 * 1024 * 2;
  bf16* k1b = (bf16*)p;              p += (size_t)4096 * 1024 * 2;
  bf16* k2b = (bf16*)p;              p += (size_t)4096 * 1024 * 2;
  bf16* yb  = (bf16*)p;              p += (size_t)4096 * 2048 * 2;

  k_cvt<<<24577, 256, 0, stream>>>(x, wq, wk, wv, wo, lq1, lk1, lq2, lk2,
                                   xb, wqb, wkb, wvb, wob, lam);
  k_gemm_qkv<<<dim3(16, 16, 3), 512, 0, stream>>>(xb, wqb, wkb, wvb,
                                                  q1b, q2b, k1b, k2b, vt);
  k_flash<<<dim3(16, 16), 512, 0, stream>>>(q1b, q2b, k1b, k2b, vt, lam, yb);
  k_gemm_out<<<dim3(16, 16), 512, 0, stream>>>(yb, wob, out);
}

// Round 7
// 399.078 us; speedup vs baseline: 1.1355x; 1.0474x over previous
//
#include <hip/hip_runtime.h>
#include <hip/hip_bf16.h>

using bf16 = __hip_bfloat16;
typedef __bf16 bf16x8_t __attribute__((ext_vector_type(8)));
typedef __bf16 bf16x4_t __attribute__((ext_vector_type(4)));
typedef float f32x4  __attribute__((ext_vector_type(4)));
typedef float f32x16 __attribute__((ext_vector_type(16)));

#define AS1 __attribute__((address_space(1)))
#define AS3 __attribute__((address_space(3)))

__device__ __forceinline__ void gll16(const void* g, void* l) {
  __builtin_amdgcn_global_load_lds((const AS1 void*)g, (AS3 void*)l, 16u, 0, 0u);
}

__device__ __forceinline__ __bf16 tobf(float f) {
  bf16 h = __float2bfloat16(f);
  return __builtin_bit_cast(__bf16, h);
}

// ---------------------------------------------------------------- cvt fp32->bf16 (+lam)
__global__ __launch_bounds__(256) void k_cvt(
    const float* __restrict__ x,  const float* __restrict__ wq,
    const float* __restrict__ wk, const float* __restrict__ wv,
    const float* __restrict__ wo,
    const float* __restrict__ lq1, const float* __restrict__ lk1,
    const float* __restrict__ lq2, const float* __restrict__ lk2,
    bf16* __restrict__ xb,  bf16* __restrict__ wqb, bf16* __restrict__ wkb,
    bf16* __restrict__ wvb, bf16* __restrict__ wob, float* __restrict__ lam) {
  if (blockIdx.x == 24576) {                 // fused lambda block
    __shared__ float r1[4], r2[4];
    int t = threadIdx.x;
    float a = lq1[t] * lk1[t];
    float b = lq2[t] * lk2[t];
#pragma unroll
    for (int s = 1; s < 64; s <<= 1) { a += __shfl_xor(a, s); b += __shfl_xor(b, s); }
    if ((t & 63) == 0) { r1[t >> 6] = a; r2[t >> 6] = b; }
    __syncthreads();
    if (t == 0) {
      float s1 = r1[0] + r1[1] + r1[2] + r1[3];
      float s2 = r2[0] + r2[1] + r2[2] + r2[3];
      *lam = expf(s1) - expf(s2) + 0.2f;
    }
    return;
  }
  size_t id = (size_t)blockIdx.x * 256 + threadIdx.x;   // float4 units
  const float* s; bf16* d; size_t off;
  if (id < 2097152) { s = x; d = xb; off = id; }
  else {
    size_t r = id - 2097152;
    unsigned w = (unsigned)(r >> 20);
    off = r & 1048575u;
    s = (w == 0) ? wq : (w == 1) ? wk : (w == 2) ? wv : wo;
    d = (w == 0) ? wqb : (w == 1) ? wkb : (w == 2) ? wvb : wob;
  }
  const float4 v = ((const float4*)s)[off];
  bf16x4_t o = { tobf(v.x), tobf(v.y), tobf(v.z), tobf(v.w) };
  *(bf16x4_t*)(d + off * 4) = o;
}

// ================================================================ 256x128 2-phase GEMM
// 512 thr (8 waves 4Mx2N, per-wave 64x64), BK=64, ring-of-3 LDS slots
// (A 3x32KB + B 3x16KB = 144 KiB). Per K-tile: 2 phases, ONE barrier per
// phase: {reads, stage, barrier, [more reads], MFMA}. Phase-2 B-half reads
// issue after the ph1 barrier -> overlap MFMA1. Stage stagger: A(t+2)@ph1,
// B(t+2)@ph2; vmcnt(6) before ph2 barrier -> tile t+1 landed before its
// reads; never drains to 0 in steady state.
#define MFMA16(a, b, c) __builtin_amdgcn_mfma_f32_16x16x32_bf16(a, b, c, 0, 0, 0)

template<bool SWAP>
__device__ __forceinline__ void gemmKS(
    const bf16* __restrict__ A, const bf16* __restrict__ B,
    int m0, int n0, bf16* lA_, bf16* lB_, f32x4 (&acc)[4][4]) {
  const int tid = threadIdx.x, lane = tid & 63;
  const int wave = tid >> 6, m = wave >> 1, n = wave & 1;   // 4M x 2N
  const int g = lane >> 4, l15 = lane & 15, l7 = lane & 7;

  auto stageA = [&](int t, int sl) {
    bf16* d = lA_ + sl * 16384;
#pragma unroll
    for (int j = 0; j < 4; ++j) {
      int id = tid + j * 512;
      int row = id >> 3, sc = (id & 7) ^ (row & 7);
      gll16(A + (size_t)(m0 + row) * 2048 + t * 64 + sc * 8, d + id * 8);
    }
  };
  auto stageB = [&](int t, int sl) {
    bf16* d = lB_ + sl * 8192;
#pragma unroll
    for (int j = 0; j < 2; ++j) {
      int id = tid + j * 512;
      int row = id >> 3, sc = (id & 7) ^ (row & 7);
      gll16(B + (size_t)(n0 + row) * 2048 + t * 64 + sc * 8, d + id * 8);
    }
  };

  // prologue: tiles 0,1 in flight (12 loads); wait tile0 (keep newest 6)
  stageA(0, 0); stageB(0, 0); stageA(1, 1); stageB(1, 1);
  asm volatile("s_waitcnt vmcnt(6)\n\ts_barrier" ::: "memory");

  int s = 0;
  for (int t = 0; t < 32; ++t) {
    const bf16* la = lA_ + s * 16384;
    const bf16* lb = lB_ + s * 8192;
    int sp = s + 2; if (sp >= 3) sp -= 3;
    bf16x8_t af[4][2], bv[4][2];

    // ---- phase 1: read A(all rf) + B(cf0,1); stage A(t+2); barrier; MFMA1
#pragma unroll
    for (int ks = 0; ks < 2; ++ks) {
      const int pc = ((ks * 4 + g) ^ l7) * 8;
#pragma unroll
      for (int rf = 0; rf < 4; ++rf)
        af[rf][ks] = *(const bf16x8_t*)(la + (m * 64 + rf * 16 + l15) * 64 + pc);
#pragma unroll
      for (int cf = 0; cf < 2; ++cf)
        bv[cf][ks] = *(const bf16x8_t*)(lb + (n * 32 + cf * 16 + l15) * 64 + pc);
    }
    if (t + 2 < 32) stageA(t + 2, sp);
    asm volatile("s_barrier" ::: "memory");
    // B(cf2,3) reads issued now -> overlap MFMA1 on the LDS pipe
#pragma unroll
    for (int ks = 0; ks < 2; ++ks) {
      const int pc = ((ks * 4 + g) ^ l7) * 8;
#pragma unroll
      for (int cf = 0; cf < 2; ++cf)
        bv[cf + 2][ks] =
            *(const bf16x8_t*)(lb + (n * 32 + cf * 16 + 64 + l15) * 64 + pc);
    }
    __builtin_amdgcn_s_setprio(1);
#pragma unroll
    for (int ks = 0; ks < 2; ++ks)
#pragma unroll
      for (int rf = 0; rf < 4; ++rf)
#pragma unroll
        for (int cf = 0; cf < 2; ++cf)
          acc[rf][cf] = SWAP ? MFMA16(bv[cf][ks], af[rf][ks], acc[rf][cf])
                             : MFMA16(af[rf][ks], bv[cf][ks], acc[rf][cf]);
    __builtin_amdgcn_s_setprio(0);

    // ---- phase 2: stage B(t+2); vmcnt(6); barrier; MFMA2
    if (t + 2 < 32) {
      stageB(t + 2, sp);
      asm volatile("s_waitcnt vmcnt(6)" ::: "memory");  // tile t+1 landed
    } else if (t == 30) {
      asm volatile("s_waitcnt vmcnt(0)" ::: "memory");  // drain tile 31
    }
    asm volatile("s_barrier" ::: "memory");
    __builtin_amdgcn_s_setprio(1);
#pragma unroll
    for (int ks = 0; ks < 2; ++ks)
#pragma unroll
      for (int rf = 0; rf < 4; ++rf)
#pragma unroll
        for (int cf = 0; cf < 2; ++cf)
          acc[rf][cf + 2] = SWAP ? MFMA16(bv[cf + 2][ks], af[rf][ks], acc[rf][cf + 2])
                                 : MFMA16(af[rf][ks], bv[cf + 2][ks], acc[rf][cf + 2]);
    __builtin_amdgcn_s_setprio(0);
    s = (s == 2) ? 0 : s + 1;
  }
}

// ---------------------------------------------------------------- QKV projection
// grid (16,16,3) = 768 blocks = exactly 3 rounds at 1 block/CU.
// BN=128 == one rms-norm group; rotary pairs wave-local via
// col = n*32 + (cf&1)*16 + (cf>>1)*64.
__global__ __launch_bounds__(512, 2) void k_gemm_qkv(
    const bf16* __restrict__ xb,
    const bf16* __restrict__ wqb, const bf16* __restrict__ wkb,
    const bf16* __restrict__ wvb,
    bf16* __restrict__ q1, bf16* __restrict__ q2,
    bf16* __restrict__ k1, bf16* __restrict__ k2,
    bf16* __restrict__ vt) {
  __shared__ __align__(16) bf16 lA[3 * 16384];        // 96 KiB
  __shared__ __align__(16) bf16 lB[3 * 8192];         // 48 KiB
  __shared__ float exs[2][256];                       // 2 KiB rms exchange
  __shared__ float lCs[64], lSn[64];
  const int z  = blockIdx.z;
  const int m0 = blockIdx.y * 256, n0 = blockIdx.x * 128;
  const int nh = blockIdx.x >> 1, p = blockIdx.x & 1;
  const int tid = threadIdx.x, lane = tid & 63, wave = tid >> 6;
  const int m = wave >> 1, n = wave & 1;
  const int g = lane >> 4, l15 = lane & 15;
  f32x4 acc[4][4] = {};

  if (z < 2) {
    if (tid < 64) {
      float fr = exp2f(-(float)tid * 0.20762050593045951f);  // log2(10000)/64
      float sn, cs;
      sincosf((float)nh * fr, &sn, &cs);
      lCs[tid] = cs; lSn[tid] = sn;
    }
    const bf16* Bm = z ? wkb : wqb;
    gemmKS<true>(xb, Bm, m0, n0, lA, lB, acc);

    // rmsnorm: block's 128 cols = one group; reduce over g then 2 n-waves
    float ssr[4];
#pragma unroll
    for (int rf = 0; rf < 4; ++rf) {
      float ss = 0.f;
#pragma unroll
      for (int cf = 0; cf < 4; ++cf)
#pragma unroll
        for (int r = 0; r < 4; ++r) ss += acc[rf][cf][r] * acc[rf][cf][r];
      ss += __shfl_xor(ss, 16);
      ss += __shfl_xor(ss, 32);
      ssr[rf] = ss;
      if (g == 0) exs[n][m * 64 + rf * 16 + l15] = ss;
    }
    __syncthreads();
    bf16* dst = z ? (p ? k2 : k1) : (p ? q2 : q1);
#pragma unroll
    for (int rf = 0; rf < 4; ++rf) {
      const int rrow = m * 64 + rf * 16 + l15;
      const float tt = ssr[rf] + exs[n ^ 1][rrow];
      const float inv = rsqrtf(tt * (1.0f / 128.0f) + 1.1920929e-07f);
      const size_t base = ((size_t)(m0 + rrow) * 8 + nh) * 128;
#pragma unroll
      for (int cf = 0; cf < 2; ++cf) {
        const int jb = n * 32 + cf * 16 + 4 * g;
        bf16x4_t o1v, o2v;
#pragma unroll
        for (int r = 0; r < 4; ++r) {
          const float cs = lCs[jb + r], sn = lSn[jb + r];
          float x1 = acc[rf][cf][r] * inv;
          float x2 = acc[rf][cf + 2][r] * inv;
          o1v[r] = tobf(x1 * cs + x2 * sn);
          o2v[r] = tobf(x2 * cs - x1 * sn);
        }
        *(bf16x4_t*)(dst + base + jb)      = o1v;
        *(bf16x4_t*)(dst + base + jb + 64) = o2v;
      }
    }
  } else {
    gemmKS<false>(xb, wvb, m0, n0, lA, lB, acc);
    // V transposed to (bh, hd, t): unswapped reg-field = 4 consecutive rows
#pragma unroll
    for (int rf = 0; rf < 4; ++rf)
#pragma unroll
      for (int cf = 0; cf < 4; ++cf) {
        const int rb = m0 + m * 64 + rf * 16 + 4 * g;
        const int col = n0 + n * 32 + (cf & 1) * 16 + (cf >> 1) * 64 + l15;
        const int hd = col & 255;
        const int b = rb >> 11, t = rb & 2047;
        bf16x4_t pv;
#pragma unroll
        for (int r = 0; r < 4; ++r) pv[r] = tobf(acc[rf][cf][r]);
        *(bf16x4_t*)(vt + ((size_t)((b * 8 + nh) * 256 + hd)) * 2048 + t) = pv;
      }
  }
}

// ---------------------------------------------------------------- output GEMM
// grid (16,16) = 256 blocks = exactly 1 round.
__global__ __launch_bounds__(512, 2) void k_gemm_out(
    const bf16* __restrict__ yb, const bf16* __restrict__ wob,
    float* __restrict__ outp) {
  __shared__ __align__(16) bf16 lA[3 * 16384];
  __shared__ __align__(16) bf16 lB[3 * 8192];
  const int m0 = blockIdx.y * 256, n0 = blockIdx.x * 128;
  const int tid = threadIdx.x, lane = tid & 63, wave = tid >> 6;
  const int m = wave >> 1, n = wave & 1;
  const int g = lane >> 4, l15 = lane & 15;
  f32x4 acc[4][4] = {};
  gemmKS<true>(yb, wob, m0, n0, lA, lB, acc);
#pragma unroll
  for (int rf = 0; rf < 4; ++rf)
#pragma unroll
    for (int cf = 0; cf < 4; ++cf) {
      const int row = m0 + m * 64 + rf * 16 + l15;
      const int col = n0 + n * 32 + (cf & 1) * 16 + (cf >> 1) * 64 + 4 * g;
      f32x4 v;
#pragma unroll
      for (int r = 0; r < 4; ++r) v[r] = acc[rf][cf][r] * 0.8f;
      *(f32x4*)(outp + (size_t)row * 2048 + col) = v;
    }
}

// ---------------------------------------------------------------- flash attention
// 256 blocks (pair, bh) x 512 thr (8 waves = at x qg x kvh). kv-split flash
// with independent online-softmax states combined in f32 at finish.
// Round-7: all cross-half exchanges via PROVEN __shfl_xor(.,32) (round-4
// semantics; permlane32_swap reverted — its half-pairing semantics are
// unverifiable from bench feedback). Kept value-neutral wins: QK 2-chain
// split, hoisted pf[2] pack, XF combine XOR-swizzle (conflict fix).
__global__ __launch_bounds__(512, 2) void k_flash(
    const bf16* __restrict__ q1b, const bf16* __restrict__ q2b,
    const bf16* __restrict__ k1b, const bf16* __restrict__ k2b,
    const bf16* __restrict__ vtb, const float* __restrict__ lamp,
    bf16* __restrict__ yb) {
  __shared__ __align__(16) bf16 smem[65536];  // 128 KB
  __shared__ float mx[8][32], lx[8][32];
  const int tid  = threadIdx.x;
  const int lane = tid & 63, wave = tid >> 6;
  const int pair = blockIdx.x;           // 0..15
  const int bh = blockIdx.y;
  const int b = bh >> 3, nh = bh & 7;
  const int at = wave & 1, qg = (wave >> 1) & 1, kvh = wave >> 2;
  const int l31 = lane & 31, g5 = lane >> 5, l7 = lane & 7;
  const float sl2e = 0.12751743f;        // (1/sqrt(128)) * log2(e)
  const float lam = *lamp;

  auto stage = [&](int kt, int buf) {
    bf16* dst = smem + buf * 32768;
    const int k0 = kt * 64;
#pragma unroll
    for (int it = 0; it < 2; ++it) {
      int id = tid + it * 512;
      int row = id >> 4, c = id & 15;
      int sc = (c & 8) | ((c & 7) ^ (row & 7));
      size_t goff = ((size_t)(b * 2048 + k0 + row) * 8 + nh) * 128 + sc * 8;
      gll16(k1b + goff, dst + id * 8);
      gll16(k2b + goff, dst + 8192 + id * 8);
    }
#pragma unroll
    for (int it = 0; it < 4; ++it) {
      int id = tid + it * 512;
      int row = id >> 3, c = id & 7;
      int sc = c ^ (row & 7);
      gll16(vtb + ((size_t)(bh * 256 + row)) * 2048 + k0 + sc * 8,
            dst + 16384 + id * 8);
    }
  };

  bf16x8_t qf[8];
  auto loadQ = [&](int qt) {
    int qglob = qt * 64 + qg * 32 + l31;
    const bf16* qp = (at ? q2b : q1b) +
                     ((size_t)(b * 2048 + qglob) * 8 + nh) * 128 + g5 * 8;
#pragma unroll
    for (int ks = 0; ks < 8; ++ks) qf[ks] = *(const bf16x8_t*)(qp + ks * 16);
  };

  f32x16 O[8];
  float mrun, lrun;
  auto resetO = [&]() {
#pragma unroll
    for (int i = 0; i < 8; ++i)
#pragma unroll
      for (int j = 0; j < 16; ++j) O[i][j] = 0.f;
    mrun = -1e30f; lrun = 0.f;
  };

  auto step = [&](int kt, int buf, int qt) {
    const int k0 = kt * 64 + kvh * 32;
    if (k0 > qt * 64 + qg * 32 + 31) return;   // all keys causal-masked
    const bf16* lk = smem + buf * 32768 + (at ? 8192 : 0);
    const bf16* lv = smem + buf * 32768 + 16384;
    const int qglob = qt * 64 + qg * 32 + l31;

    // QK^T: two 4-deep accumulation chains instead of one 8-deep
    f32x16 s0, sx;
#pragma unroll
    for (int j = 0; j < 16; ++j) { s0[j] = 0.f; sx[j] = 0.f; }
#pragma unroll
    for (int ks = 0; ks < 8; ++ks) {
      int cl = ks * 2 + g5;
      int pc = (cl & 8) | ((cl & 7) ^ l7);
      bf16x8_t a0 = *(const bf16x8_t*)(lk + (kvh * 32 + l31) * 128 + pc * 8);
      if (ks < 4)
        s0 = __builtin_amdgcn_mfma_f32_32x32x16_bf16(a0, qf[ks], s0, 0, 0, 0);
      else
        sx = __builtin_amdgcn_mfma_f32_32x32x16_bf16(a0, qf[ks], sx, 0, 0, 0);
    }

    const bool needmask = (k0 + 31 > qt * 64 + qg * 32);
    float rmax = -3.0e38f;
#pragma unroll
    for (int r = 0; r < 16; ++r) {
      float v0 = (s0[r] + sx[r]) * sl2e;       // log2-domain scores
      if (needmask) {
        int key0 = k0 + (r & 3) + 8 * (r >> 2) + 4 * g5;
        if (key0 > qglob) v0 = -1e30f;
      }
      s0[r] = v0;
      rmax = fmaxf(rmax, v0);
    }
    rmax = fmaxf(rmax, __shfl_xor(rmax, 32));
    if (!__all(rmax - mrun <= 8.0f)) {         // defer-max: P bounded by 2^8
      float mnew = fmaxf(mrun, rmax);
      float alpha = exp2f(mrun - mnew);
      lrun *= alpha;
#pragma unroll
      for (int i = 0; i < 8; ++i) O[i] *= alpha;
      mrun = mnew;
    }
    float psum = 0.f;
#pragma unroll
    for (int r = 0; r < 16; ++r) {
      float p0 = exp2f(s0[r] - mrun);
      s0[r] = p0;
      psum += p0;
    }
    psum += __shfl_xor(psum, 32);
    lrun += psum;

    // pack BOTH P slices first (proven round-4 shfl_xor path), then PV
    bf16x8_t pf[2];
#pragma unroll
    for (int sl = 0; sl < 2; ++sl) {
      bf16x4_t lo, hi;
#pragma unroll
      for (int j = 0; j < 4; ++j) {
        lo[j] = tobf(s0[sl * 8 + j]);
        hi[j] = tobf(s0[sl * 8 + 4 + j]);
      }
      bf16x4_t send = g5 ? lo : hi;
      int2 si = __builtin_bit_cast(int2, send);
      int2 ri;
      ri.x = __shfl_xor(si.x, 32);
      ri.y = __shfl_xor(si.y, 32);
      bf16x4_t recv = __builtin_bit_cast(bf16x4_t, ri);
      bf16x4_t f0 = g5 ? recv : lo;
      bf16x4_t f1 = g5 ? hi : recv;
      pf[sl] = bf16x8_t{ f0[0], f0[1], f0[2], f0[3], f1[0], f1[1], f1[2], f1[3] };
    }

    // PV: all V reads + MFMAs flow with no pack stalls interleaved
#pragma unroll
    for (int sl = 0; sl < 2; ++sl) {
      const int cl = kvh * 4 + sl * 2 + g5;
#pragma unroll
      for (int mt = 0; mt < 8; ++mt) {
        bf16x8_t vf = *(const bf16x8_t*)(lv + (mt * 32 + l31) * 64 + (cl ^ l7) * 8);
        O[mt] = __builtin_amdgcn_mfma_f32_32x32x16_bf16(vf, pf[sl], O[mt], 0, 0, 0);
      }
    }
  };

  auto finish = [&](int qt, bf16* cbuf) {
    const int qglob = qt * 64 + qg * 32 + l31;
    float* XF = (float*)cbuf;                  // 64 KB = 16384 f32, free buffer
    const int hsw = (l31 & 7) << 2;            // bank swizzle for the exchange
    __syncthreads();                           // all waves done reading cbuf
    if (g5 == 0) { mx[wave][l31] = mrun; lx[wave][l31] = lrun; }
    __syncthreads();
    const float mo  = mx[wave ^ 4][l31];
    const float lo2 = lx[wave ^ 4][l31];
    const float ms = fmaxf(mrun, mo);
    const float ws = exp2f(mrun - ms);         // own weight (0 if state empty)
    const float wo = exp2f(mo - ms);
    const float lstar = lrun * ws + lo2 * wo;
    // two rounds of f32 O-combine (64 KB holds 2 waves' O at a time)
#pragma unroll
    for (int rnd = 0; rnd < 2; ++rnd) {
      if (at == rnd && kvh == 1) {
#pragma unroll
        for (int mt = 0; mt < 8; ++mt)
#pragma unroll
          for (int rq = 0; rq < 4; ++rq) {
            int hd = (mt * 32 + 8 * rq + 4 * g5) ^ hsw;
            f32x4 v;
#pragma unroll
            for (int i = 0; i < 4; ++i) v[i] = O[mt][rq * 4 + i] * ws;
            *(f32x4*)(XF + qg * 8192 + l31 * 256 + hd) = v;
          }
      }
      __syncthreads();
      if (at == rnd && kvh == 0) {
#pragma unroll
        for (int mt = 0; mt < 8; ++mt)
#pragma unroll
          for (int rq = 0; rq < 4; ++rq) {
            int hd = (mt * 32 + 8 * rq + 4 * g5) ^ hsw;
            f32x4 v = *(const f32x4*)(XF + qg * 8192 + l31 * 256 + hd);
#pragma unroll
            for (int i = 0; i < 4; ++i)
              O[mt][rq * 4 + i] = O[mt][rq * 4 + i] * ws + v[i];
          }
      }
      __syncthreads();
    }
    // branch subtraction among kvh=0 waves (cbuf reusable as bf16 now)
    const float invl = 1.f / lstar;
    if (kvh == 0 && at == 1) {
      const float f = lam * invl;
#pragma unroll
      for (int mt = 0; mt < 8; ++mt)
#pragma unroll
        for (int rq = 0; rq < 4; ++rq) {
          int hd = mt * 32 + 8 * rq + 4 * g5;
          bf16x4_t pv;
#pragma unroll
          for (int i = 0; i < 4; ++i) pv[i] = tobf(O[mt][rq * 4 + i] * f);
          *(bf16x4_t*)(cbuf + (size_t)(qg * 32 + l31) * 264 + hd) = pv;
        }
    }
    __syncthreads();
    if (kvh == 0 && at == 0) {
#pragma unroll
      for (int mt = 0; mt < 8; ++mt)
#pragma unroll
        for (int rq = 0; rq < 4; ++rq) {
          int hd = mt * 32 + 8 * rq + 4 * g5;
          bf16x4_t o2 = *(const bf16x4_t*)(cbuf + (size_t)(qg * 32 + l31) * 264 + hd);
          bf16x4_t pv;
#pragma unroll
          for (int i = 0; i < 4; ++i)
            pv[i] = tobf(O[mt][rq * 4 + i] * invl - (float)o2[i]);
          *(bf16x4_t*)(yb + (size_t)(b * 2048 + qglob) * 2048 + nh * 256 + hd) = pv;
        }
    }
  };

  const int qtB = 31 - pair, qtA = pair;

  loadQ(qtB);
  resetO();
  stage(0, 0);
  for (int kt = 0; kt <= qtB; ++kt) {
    __syncthreads();
    if (kt < qtB) stage(kt + 1, (kt + 1) & 1);
    else          stage(0, (kt + 1) & 1);        // prefetch segment A kt=0
    step(kt, kt & 1, qtB);
  }
  finish(qtB, smem + (qtB & 1) * 32768);

  loadQ(qtA);
  resetO();
  for (int kt = 0; kt <= qtA; ++kt) {
    __syncthreads();
    if (kt < qtA) stage(kt + 1, (qtB + kt + 2) & 1);
    step(kt, (qtB + 1 + kt) & 1, qtA);
  }
  finish(qtA, smem + 32768);
}

// ---------------------------------------------------------------- launch
extern "C" void kernel_launch(void* const* d_in, const int* in_sizes, int n_in,
                              void* d_out, int out_size, void* d_ws, size_t ws_size,
                              hipStream_t stream) {
  (void)in_sizes; (void)n_in; (void)out_size; (void)ws_size;
  const float* x   = (const float*)d_in[0];
  const float* wq  = (const float*)d_in[1];
  const float* wk  = (const float*)d_in[2];
  const float* wv  = (const float*)d_in[3];
  const float* wo  = (const float*)d_in[4];
  const float* lq1 = (const float*)d_in[5];
  const float* lk1 = (const float*)d_in[6];
  const float* lq2 = (const float*)d_in[7];
  const float* lk2 = (const float*)d_in[8];
  float* out = (float*)d_out;

  char* p = (char*)d_ws;
  float* lam = (float*)p;            p += 256;
  bf16* xb  = (bf16*)p;              p += (size_t)4096 * 2048 * 2;
  bf16* wqb = (bf16*)p;              p += (size_t)2048 * 2048 * 2;
  bf16* wkb = (bf16*)p;              p += (size_t)2048 * 2048 * 2;
  bf16* wvb = (bf16*)p;              p += (size_t)2048 * 2048 * 2;
  bf16* wob = (bf16*)p;              p += (size_t)2048 * 2048 * 2;
  bf16* vt  = (bf16*)p;              p += (size_t)4096 * 2048 * 2;
  bf16* q1b = (bf16*)p;              p += (size_t)4096 * 1024 * 2;
  bf16* q2b = (bf16*)p;              p += (size_t)4096 * 1024 * 2;
  bf16* k1b = (bf16*)p;              p += (size_t)4096 * 1024 * 2;
  bf16* k2b = (bf16*)p;              p += (size_t)4096 * 1024 * 2;
  bf16* yb  = (bf16*)p;              p += (size_t)4096 * 2048 * 2;

  k_cvt<<<24577, 256, 0, stream>>>(x, wq, wk, wv, wo, lq1, lk1, lq2, lk2,
                                   xb, wqb, wkb, wvb, wob, lam);
  k_gemm_qkv<<<dim3(16, 16, 3), 512, 0, stream>>>(xb, wqb, wkb, wvb,
                                                  q1b, q2b, k1b, k2b, vt);
  k_flash<<<dim3(16, 16), 512, 0, stream>>>(q1b, q2b, k1b, k2b, vt, lam, yb);
  k_gemm_out<<<dim3(16, 16), 512, 0, stream>>>(yb, wob, out);
}